// Round 19
// baseline (376.048 us; speedup 1.0000x reference)
//
#include <hip/hip_runtime.h>
#include <math.h>

constexpr int R_ = 128, C_ = 64, NL_ = 2, B_ = 2, V_ = 4;
constexpr int N_ = R_ * R_;          // 16384
constexpr int T_ = 6;

typedef __attribute__((ext_vector_type(8))) short bf16x8;
typedef __attribute__((ext_vector_type(4))) float f32x4;
typedef __attribute__((ext_vector_type(4))) unsigned short u16x4;
typedef __attribute__((ext_vector_type(8))) unsigned short u16x8;
typedef __attribute__((ext_vector_type(2))) __fp16 h2;

#define MFMA_B16(a, b, c) __builtin_amdgcn_mfma_f32_16x16x32_bf16((a), (b), (c), 0, 0, 0)

// packed-weight element offsets (per layer, in elements)
constexpr int OFF_O = 12288, OFF_W1 = 16384, OFF_W2 = 32768;
constexpr int PK_ELEMS = 49152;
constexpr int LAYER_PK = 2 * PK_ELEMS;   // ushorts per layer (hi+lo)

// splat-path sizes
constexpr int NBV = B_ * V_;                       // 8
constexpr size_t FTR_SZ = (size_t)NBV * N_ * C_;   // 8,388,608 floats
constexpr int NSEG = 3 * NBV;                      // 24 segments
constexpr size_t SEG_SZ = (size_t)NSEG * N_;       // 393,216 ints
constexpr int OSTRIDE = N_ + 128;                  // offsets stride (sentinel pad)
constexpr size_t KV_SZ = (size_t)3 * B_ * T_ * 128 * 64;   // 294,912 floats

// ---------- helpers ----------
__device__ inline unsigned rne16(float x) {
    unsigned b = __float_as_uint(x);
    return (b + 0x7fffu + ((b >> 16) & 1u)) >> 16;
}

__device__ inline float wsum(float v) {
#pragma unroll
    for (int m = 1; m < 64; m <<= 1) v += __shfl_xor(v, m, 64);
    return v;
}

__device__ inline float lnorm(float v, float g, float b) {
    float m = wsum(v) * (1.f / 64.f);
    float d = v - m;
    float var = wsum(d * d) * (1.f / 64.f);
    return d * rsqrtf(var + 1e-5f) * g + b;
}

// stage a 64x64 row-major fp32 matrix into LDS buf[c*68 + u]
__device__ inline void stageW(const float* __restrict__ W, float* buf, int tid) {
#pragma unroll
    for (int it = 0; it < 4; ++it) {
        int idx4 = it * 256 + tid;
        int r = idx4 >> 4, u4 = idx4 & 15;
        float4 v = ((const float4*)W)[idx4];
        *(float4*)&buf[r * 68 + u4 * 4] = v;
    }
}

// read A-fragment (16x32 bf16) for wave's M-tile from swizzled LDS
__device__ inline bf16x8 readFrag(const unsigned short* base, int rowBase, int lane,
                                  int ks, int rowStrideB, int swzMask) {
    int rowloc = rowBase + (lane & 15);
    int off = rowloc * rowStrideB + ks * 64 + ((lane >> 4) & 3) * 16;
    off ^= ((rowloc & swzMask) << 4);
    return *(const bf16x8*)((const char*)base + off);
}

// store 4 bf16-hi values (K-permuted: p = cb*4+nt) as one 8B write
__device__ inline void storeA4(unsigned short* base, int rloc, int cb,
                               float v0, float v1, float v2, float v3) {
    u16x4 u;
    u[0] = (unsigned short)rne16(v0);
    u[1] = (unsigned short)rne16(v1);
    u[2] = (unsigned short)rne16(v2);
    u[3] = (unsigned short)rne16(v3);
    int bo = (rloc * 128 + cb * 8) ^ ((rloc & 7) << 4);
    *(u16x4*)((char*)base + bo) = u;
}

// load B-fragment pair (hi,lo) from a weight table (global or LDS)
__device__ inline void readB(const unsigned short* matHi, int E, int NTm, int ks, int nt,
                             int lane, bf16x8& bh, bf16x8& bl) {
    int off = (((ks * NTm + nt) << 6) + lane) << 3;
    bh = *(const bf16x8*)(matHi + off);
    bl = *(const bf16x8*)(matHi + E + off);
}

// ---------- pack all weights of one layer (K-permuted, split hi/lo) ----------
__global__ __launch_bounds__(256) void pack_layer(const float* __restrict__ iw,
                                                  const float* __restrict__ ow,
                                                  const float* __restrict__ w1,
                                                  const float* __restrict__ w2,
                                                  unsigned short* __restrict__ pk) {
    int idx = blockIdx.x * 256 + threadIdx.x;
    if (idx >= PK_ELEMS) return;
    const float* W;
    int O, K, base, mode, lidx;
    if (idx < 12288)      { int m = idx >> 12; lidx = idx & 4095; W = iw + m * 4096; O = 64;  K = 64;  base = m * 4096; mode = 0; }
    else if (idx < 16384) { lidx = idx - 12288; W = ow; O = 64;  K = 64;  base = OFF_O;  mode = 0; }
    else if (idx < 32768) { lidx = idx - 16384; W = w1; O = 256; K = 64;  base = OFF_W1; mode = 0; }
    else                  { lidx = idx - 32768; W = w2; O = 64;  K = 256; base = OFF_W2; mode = 1; }
    int j = lidx & 7, l = (lidx >> 3) & 63, rem = lidx >> 9;
    int NTm = O >> 4;
    int nt = rem & (NTm - 1), ks = rem / NTm;
    int kfrag = ks * 32 + ((l >> 4) & 3) * 8 + j;
    int k;
    if (mode == 0) { int p = kfrag & 63; k = (p & 3) * 16 + (p >> 2); }
    else { int cc = kfrag >> 7; int pl = kfrag & 127; k = (cc * 8 + (pl & 7)) * 16 + (pl >> 3); }
    int o = nt * 16 + (l & 15);
    float w = W[(size_t)o * K + k];
    unsigned hb = rne16(w);
    float hf = __uint_as_float(hb << 16);
    unsigned lb = rne16(w - hf);
    int E = O * K;
    pk[2 * base + lidx] = (unsigned short)hb;
    pk[2 * base + E + lidx] = (unsigned short)lb;
}

// ---------- zero bin counts ----------
__global__ __launch_bounds__(256) void zero_counts(int4* __restrict__ p, int n4) {
    int i = blockIdx.x * 256 + threadIdx.x;
    if (i < n4) p[i] = make_int4(0, 0, 0, 0);
}

// ---------- transpose features: [bv][c][n] -> [bv][n][c] ----------
__global__ __launch_bounds__(256) void transpose_feats(const float* __restrict__ src,
                                                       float* __restrict__ dst) {
    __shared__ float tile[64][65];
    int blk = blockIdx.x;             // NBV * 256
    int ntile = blk & 255;
    int bv = blk >> 8;
    int n0 = ntile * 64;
    int tr = threadIdx.x >> 6, tc = threadIdx.x & 63;
    const float* s = src + (size_t)bv * C_ * N_;
#pragma unroll
    for (int it = 0; it < 16; ++it) {
        int c = it * 4 + tr;
        tile[c][tc] = s[(size_t)c * N_ + n0 + tc];
    }
    __syncthreads();
    float* d = dst + ((size_t)bv * N_ + n0) * C_;
#pragma unroll
    for (int it = 0; it < 16; ++it) {
        int r = it * 4 + tr;
        d[(size_t)r * C_ + tc] = tile[tc][r];
    }
}

// ---------- bin count ----------
__global__ __launch_bounds__(256) void bin_count(const float* __restrict__ pts,
                                                 int* __restrict__ counts) {
    int idx = blockIdx.x * 256 + threadIdx.x;     // [0, NBV*N)
    if (idx >= NBV * N_) return;
    int bv = idx >> 14;
    const float* p = pts + (size_t)idx * 3;
    float px = p[0], py = p[1], pz = p[2];
    const float HI = (float)(127.0 - 1e-5);
    float gx = fminf(fmaxf((px + 1.0f) * 127.0f / 2.0f, 0.0f), HI);
    float gy = fminf(fmaxf((py + 1.0f) * 127.0f / 2.0f, 0.0f), HI);
    float gz = fminf(fmaxf((pz + 1.0f) * 127.0f / 2.0f, 0.0f), HI);
    int x0 = (int)gx, y0 = (int)gy, z0 = (int)gz;
    atomicAdd(&counts[(0 * NBV + bv) * N_ + x0 * R_ + y0], 1);
    atomicAdd(&counts[(1 * NBV + bv) * N_ + x0 * R_ + z0], 1);
    atomicAdd(&counts[(2 * NBV + bv) * N_ + y0 * R_ + z0], 1);
}

// ---------- per-segment exclusive scan (16384 bins each) + sentinel pad ----------
__global__ __launch_bounds__(256) void scan_bins(const int* __restrict__ counts,
                                                 int* __restrict__ offsets,
                                                 int* __restrict__ cursors) {
    __shared__ int part[256];
    int seg = blockIdx.x;             // 24
    int t = threadIdx.x;
    const int* c = counts + (size_t)seg * N_;
    int sum = 0;
    for (int i = 0; i < 64; ++i) sum += c[t * 64 + i];
    part[t] = sum;
    __syncthreads();
    if (t == 0) {
        int run = 0;
        for (int i = 0; i < 256; ++i) { int v = part[i]; part[i] = run; run += v; }
    }
    __syncthreads();
    int run = part[t];
    int* o = offsets + (size_t)seg * OSTRIDE;
    int* cu = cursors + (size_t)seg * N_;
    for (int i = 0; i < 64; ++i) {
        o[t * 64 + i] = run;
        cu[t * 64 + i] = run;
        run += c[t * 64 + i];
    }
    if (t < 128) o[N_ + t] = N_;      // sentinel: total per segment == N_
}

// ---------- scatter records (n, fp16 weight pairs) into bin-sorted lists ----------
__global__ __launch_bounds__(256) void scatter_pts(const float* __restrict__ pts,
                                                   int* __restrict__ cursors,
                                                   float4* __restrict__ ent) {
    int idx = blockIdx.x * 256 + threadIdx.x;
    if (idx >= NBV * N_) return;
    int bv = idx >> 14, n = idx & (N_ - 1);
    const float* p = pts + (size_t)idx * 3;
    float px = p[0], py = p[1], pz = p[2];
    const float HI = (float)(127.0 - 1e-5);
    float gx = fminf(fmaxf((px + 1.0f) * 127.0f / 2.0f, 0.0f), HI);
    float gy = fminf(fmaxf((py + 1.0f) * 127.0f / 2.0f, 0.0f), HI);
    float gz = fminf(fmaxf((pz + 1.0f) * 127.0f / 2.0f, 0.0f), HI);
    int x0 = (int)gx, y0 = (int)gy, z0 = (int)gz;
    float wx = gx - (float)x0, wy = gy - (float)y0, wz = gz - (float)z0;
    float ax = 1.f - wx, ay = 1.f - wy, az = 1.f - wz;
    float4 e;
    e.x = __uint_as_float((unsigned)n);
    e.w = 0.f;
    int s0 = 0 * NBV + bv, s1 = 1 * NBV + bv, s2 = 2 * NBV + bv;
    // plane0 (bin row x0, col y0): dr0 -> {w000, w010}; dr1 -> {w100, w110}
    {
        h2 a = __builtin_amdgcn_cvt_pkrtz(ax * ay * az, ax * wy * az);
        h2 bq = __builtin_amdgcn_cvt_pkrtz(wx * ay * az, wx * wy * az);
        e.y = *(float*)&a; e.z = *(float*)&bq;
        int p0 = atomicAdd(&cursors[(size_t)s0 * N_ + x0 * R_ + y0], 1);
        ent[(size_t)s0 * N_ + p0] = e;
    }
    // plane1 (bin row x0, col z0): dr0 -> {w000, w001}; dr1 -> {w100, w111}
    {
        h2 a = __builtin_amdgcn_cvt_pkrtz(ax * ay * az, ax * ay * wz);
        h2 bq = __builtin_amdgcn_cvt_pkrtz(wx * ay * az, wx * wy * wz);
        e.y = *(float*)&a; e.z = *(float*)&bq;
        int p1 = atomicAdd(&cursors[(size_t)s1 * N_ + x0 * R_ + z0], 1);
        ent[(size_t)s1 * N_ + p1] = e;
    }
    // plane2 (bin row y0, col z0): dr0 -> {w000, w001}; dr1 -> {w010, w111}
    {
        h2 a = __builtin_amdgcn_cvt_pkrtz(ax * ay * az, ax * ay * wz);
        h2 bq = __builtin_amdgcn_cvt_pkrtz(ax * wy * az, wx * wy * wz);
        e.y = *(float*)&a; e.z = *(float*)&bq;
        int p2 = atomicAdd(&cursors[(size_t)s2 * N_ + y0 * R_ + z0], 1);
        ent[(size_t)s2 * N_ + p2] = e;
    }
}

// ---------- gather splat: block = 8-cell strip; wave = (view, bin-row) ----------
// register accumulators (compile-time j), fp16 precomputed weights, fused query init
__global__ __launch_bounds__(512) void gather_splat(
    const float* __restrict__ ftr, const int* __restrict__ offsets,
    const float4* __restrict__ ent, const float* __restrict__ query,
    float* __restrict__ f0) {
    __shared__ float sfacc[8][8][64];
    __shared__ float swsum[8][8];
    int wid = threadIdx.x >> 6, lane = threadIdx.x & 63;
    int v = wid >> 1, dr = wid & 1;
    int strip = blockIdx.x;                   // [0, 2048)
    int pi = blockIdx.y, b = blockIdx.z;
    int a = strip >> 4;                       // cell row
    int c0 = (strip & 15) << 3;               // first cell col of strip

    int bv = b * V_ + v;
    int seg = pi * NBV + bv;
    const int* ob = offsets + (size_t)seg * OSTRIDE;
    const float4* eb = ent + (size_t)seg * N_;
    const float* fbase = ftr + (size_t)bv * N_ * C_ + lane;
    float facc[8], wsum_[8];
#pragma unroll
    for (int k = 0; k < 8; ++k) { facc[k] = 0.f; wsum_[k] = 0.f; }

    int ba = a - dr;
    if (ba >= 0) {
        int rowbase = ba * R_ + c0 - 1;
        int o[10];
#pragma unroll
        for (int jj = 0; jj < 10; ++jj)
            o[jj] = ob[max(rowbase + jj, 0)];
#pragma unroll
        for (int j = 0; j < 9; ++j) {
            if (j == 0 && c0 == 0) continue;    // bin col -1 doesn't exist
            int e = o[j + 1];
            for (int i = o[j]; i < e; ++i) {
                float4 r = eb[i];
                int n = (int)(__float_as_uint(r.x) & 16383u);
                float pr = dr ? r.z : r.y;
                h2 ph = *(h2*)&pr;
                float w0 = (float)ph[0], w1 = (float)ph[1];
                float f = fbase[(size_t)n * C_];
                if (j > 0) { facc[j - 1] += w0 * f; wsum_[j - 1] += w0; }
                if (j < 8) { facc[j] += w1 * f; wsum_[j] += w1; }
            }
        }
    }
#pragma unroll
    for (int k = 0; k < 8; ++k) sfacc[wid][k][lane] = facc[k];
    if (lane == 0) {
#pragma unroll
        for (int k = 0; k < 8; ++k) swsum[wid][k] = wsum_[k];
    }
    __syncthreads();

    // combine: wave wid handles cell k = wid (sum dr pair per view, then normalize)
    int k = wid;
    int cell = a * R_ + c0 + k;
    float tot = 0.f;
#pragma unroll
    for (int v2 = 0; v2 < 4; ++v2) {
        float fa = sfacc[v2 * 2][k][lane] + sfacc[v2 * 2 + 1][k][lane];
        float wsv = swsum[v2 * 2][k] + swsum[v2 * 2 + 1][k];
        tot += fa / fmaxf(wsv, 1e-8f);
    }
    float qv = query[((size_t)pi * N_ + cell) * C_ + lane];
    f0[(((size_t)(pi * B_ + b)) * N_ + cell) * C_ + lane] = qv + 0.25f * tot;
}

// ---------- ctx k/v table: 4608 rows = (pi, b, t, pos) ----------
__global__ __launch_bounds__(256) void ctx_kv(
    const float* __restrict__ fin,
    const float* __restrict__ ln1g, const float* __restrict__ ln1b,
    const float* __restrict__ inw, const float* __restrict__ inb,
    float* __restrict__ kvk, float* __restrict__ kvv) {
    __shared__ float s_wk[64 * 68];
    __shared__ float s_wv[64 * 68];
    __shared__ float s_act[32 * 68];
    int tid = threadIdx.x, wid = tid >> 6, lane = tid & 63;
    stageW(inw + 4096, s_wk, tid);     // Wk
    stageW(inw + 8192, s_wv, tid);     // Wv

    int rid0 = blockIdx.x * 32 + wid * 8;
    int seg = rid0 >> 7;               // (pi*2+b)*6 + t
    int pos0 = rid0 & 127;
    int t = seg % 6;
    int pib = seg / 6;
    int pi = pib >> 1, b = pib & 1;
    int khalf = (t < 3) ? t : t - 3;
    float sk = (float)(khalf - 1);
    bool tl = t < 3;
    int io;
    if (pi == 0) io = tl ? 1 : 2;
    else if (pi == 1) io = tl ? 0 : 2;
    else io = tl ? 0 : 1;
    const float* Fio = fin + (size_t)(io * B_ + b) * N_ * 64;
    float g1 = ln1g[lane], b1 = ln1b[lane];

#pragma unroll
    for (int rr = 0; rr < 8; ++rr) {
        int pos = pos0 + rr;
        float lp = -1.0f + (2.0f * (float)pos) / 127.0f;
        float caf, cbf;
        if (pi == 0) { caf = lp; cbf = sk; }
        else if (pi == 1) { if (tl) { caf = lp; cbf = sk; } else { caf = sk; cbf = lp; } }
        else { caf = sk; cbf = lp; }
        float ua = fminf(fmaxf((caf * 0.5f + 0.5f) * 127.0f, 0.0f), 127.0f);
        float ub = fminf(fmaxf((cbf * 0.5f + 0.5f) * 127.0f, 0.0f), 127.0f);
        float gxp = fminf(fmaxf(((ua + 1.0f) * 0.5f) * 127.0f, 0.0f), 127.0f);
        float gyp = fminf(fmaxf(((ub + 1.0f) * 0.5f) * 127.0f, 0.0f), 127.0f);
        int xx0 = (int)gxp, yy0 = (int)gyp;
        int xx1 = xx0 + 1 < 128 ? xx0 + 1 : 127;
        int yy1 = yy0 + 1 < 128 ? yy0 + 1 : 127;
        float wx = gxp - (float)xx0, wy = gyp - (float)yy0;
        float v00 = Fio[(size_t)(yy0 * R_ + xx0) * 64 + lane];
        float v01 = Fio[(size_t)(yy0 * R_ + xx1) * 64 + lane];
        float v10 = Fio[(size_t)(yy1 * R_ + xx0) * 64 + lane];
        float v11 = Fio[(size_t)(yy1 * R_ + xx1) * 64 + lane];
        float cv = (1.0f - wy) * ((1.0f - wx) * v00 + wx * v01) +
                   wy * ((1.0f - wx) * v10 + wx * v11);
        s_act[(wid * 8 + rr) * 68 + lane] = lnorm(cv, g1, b1);
    }
    __syncthreads();

    float kk[8], vv[8];
    float bk = inb[64 + lane], bv = inb[128 + lane];
#pragma unroll
    for (int rr = 0; rr < 8; ++rr) { kk[rr] = bk; vv[rr] = bv; }
    const float* wrk = s_wk + lane * 68;
    const float* wrv = s_wv + lane * 68;
#pragma unroll 4
    for (int g = 0; g < 16; ++g) {
        float4 wk4 = *(const float4*)(wrk + g * 4);
        float4 wv4 = *(const float4*)(wrv + g * 4);
#pragma unroll
        for (int rr = 0; rr < 8; ++rr) {
            float4 xv = *(const float4*)(s_act + (wid * 8 + rr) * 68 + g * 4);
            kk[rr] = fmaf(xv.x, wk4.x, fmaf(xv.y, wk4.y, fmaf(xv.z, wk4.z, fmaf(xv.w, wk4.w, kk[rr]))));
            vv[rr] = fmaf(xv.x, wv4.x, fmaf(xv.y, wv4.y, fmaf(xv.z, wv4.z, fmaf(xv.w, wv4.w, vv[rr]))));
        }
    }
#pragma unroll
    for (int rr = 0; rr < 8; ++rr) {
        size_t o = ((size_t)seg * 128 + pos0 + rr) * 64 + lane;
        kvk[o] = kk[rr];
        kvv[o] = vv[rr];
    }
}

// ---------- fused per-plane transformer layer (MFMA, precomputed k/v, 40 KB LDS) ----------
__global__ __launch_bounds__(256, 3) void plane_mfma(
    const float* __restrict__ fin, float* __restrict__ fout,
    const unsigned short* __restrict__ pk,
    const float* __restrict__ kvk, const float* __restrict__ kvv,
    const float* __restrict__ ln1g, const float* __restrict__ ln1b,
    const float* __restrict__ ln2g, const float* __restrict__ ln2b,
    const float* __restrict__ inb, const float* __restrict__ outb,
    const float* __restrict__ fb1, const float* __restrict__ fb2) {
    __shared__ __attribute__((aligned(16))) unsigned short Wb[8192];   // 16 KB weight stage
    __shared__ __attribute__((aligned(16))) unsigned short Ahi[4096];  // 8 KB A-frags
    __shared__ __attribute__((aligned(16))) float Hf[4096];            // 16 KB H-frags / out stage
    unsigned short* Hhi = (unsigned short*)Hf;

    const int tid = threadIdx.x;
    const int wid = tid >> 6, lane = tid & 63;
    const int cg = lane >> 4, cb = lane & 15;
    const int pi = blockIdx.y;
    const int R0 = wid * 16;
    const int rowbase = blockIdx.x * 64;
    const int b = rowbase >> 14;
    const int nn0 = rowbase & (N_ - 1);
    const int i0 = nn0 >> 7, j0 = nn0 & 127;

    // ---- stage Q (hi+lo, 16 KB) into Wb
#pragma unroll
    for (int i = 0; i < 4; ++i)
        *(u16x8*)(Wb + (i * 256 + tid) * 8) = *(const u16x8*)(pk + (i * 256 + tid) * 8);

    float g1[4], b1v[4];
#pragma unroll
    for (int nt = 0; nt < 4; ++nt) { g1[nt] = ln1g[nt * 16 + cb]; b1v[nt] = ln1b[nt * 16 + cb]; }

    // ---- Phase A: load x (kept in regs), LN1 -> A-frags (wave-private LDS rows)
    float x[4][4];
    const float* finp = fin + ((size_t)(pi * B_ + b) * N_ + nn0) * 64;
#pragma unroll
    for (int reg = 0; reg < 4; ++reg) {
        int rloc = R0 + cg * 4 + reg;
#pragma unroll
        for (int nt = 0; nt < 4; ++nt) x[reg][nt] = finp[(size_t)rloc * 64 + nt * 16 + cb];
        float s = x[reg][0] + x[reg][1] + x[reg][2] + x[reg][3];
#pragma unroll
        for (int m = 1; m < 16; m <<= 1) s += __shfl_xor(s, m, 64);
        float mean = s * (1.0f / 64.0f);
        float d0 = x[reg][0] - mean, d1 = x[reg][1] - mean, d2 = x[reg][2] - mean, d3 = x[reg][3] - mean;
        float sq = d0 * d0 + d1 * d1 + d2 * d2 + d3 * d3;
#pragma unroll
        for (int m = 1; m < 16; m <<= 1) sq += __shfl_xor(sq, m, 64);
        float rr = rsqrtf(sq * (1.0f / 64.0f) + 1e-5f);
        storeA4(Ahi, rloc, cb,
                d0 * rr * g1[0] + b1v[0], d1 * rr * g1[1] + b1v[1],
                d2 * rr * g1[2] + b1v[2], d3 * rr * g1[3] + b1v[3]);
    }
    __syncthreads();

    // ---- Phase B: q = xn @ Wq^T + bq  (Wb = Q)
    f32x4 qa[4];
#pragma unroll
    for (int nt = 0; nt < 4; ++nt) { float bq = inb[nt * 16 + cb]; qa[nt] = {bq, bq, bq, bq}; }
#pragma unroll
    for (int ks = 0; ks < 2; ++ks) {
        bf16x8 ah = readFrag(Ahi, R0, lane, ks, 128, 7);
#pragma unroll
        for (int nt = 0; nt < 4; ++nt) {
            bf16x8 bh, bl;
            readB(Wb, 4096, 4, ks, nt, lane, bh, bl);
            qa[nt] = MFMA_B16(ah, bh, qa[nt]);
            qa[nt] = MFMA_B16(ah, bl, qa[nt]);
        }
    }

    // ---- Phase C: attention with precomputed k/v (no barriers, no LDS)
    const float* kvkb = kvk + (size_t)((pi * 2 + b) * 6) * 128 * 64;
    const float* kvvb = kvv + (size_t)((pi * 2 + b) * 6) * 128 * 64;
    float den_[4][4];
    f32x4 oa[4];
#pragma unroll
    for (int nt = 0; nt < 4; ++nt) {
        oa[nt] = {0.f, 0.f, 0.f, 0.f};
#pragma unroll
        for (int reg = 0; reg < 4; ++reg) den_[nt][reg] = 0.f;
    }

    // t = 0..2: k/v depend on j (per-row)
#pragma unroll
    for (int t = 0; t < 3; ++t) {
        float kvr[4][4], vvr[4][4];
#pragma unroll
        for (int reg = 0; reg < 4; ++reg) {
            int pos = j0 + R0 + cg * 4 + reg;
            const float* kr = kvkb + ((size_t)t * 128 + pos) * 64 + cb;
            const float* vr = kvvb + ((size_t)t * 128 + pos) * 64 + cb;
#pragma unroll
            for (int nt = 0; nt < 4; ++nt) {
                kvr[reg][nt] = kr[nt * 16];
                vvr[reg][nt] = vr[nt * 16];
            }
        }
#pragma unroll
        for (int nt = 0; nt < 4; ++nt) {
            float d0 = qa[nt][0] * kvr[0][nt];
            float d1 = qa[nt][1] * kvr[1][nt];
            float d2 = qa[nt][2] * kvr[2][nt];
            float d3 = qa[nt][3] * kvr[3][nt];
#pragma unroll
            for (int m = 1; m < 16; m <<= 1) {
                d0 += __shfl_xor(d0, m, 64);
                d1 += __shfl_xor(d1, m, 64);
                d2 += __shfl_xor(d2, m, 64);
                d3 += __shfl_xor(d3, m, 64);
            }
            float e0 = __expf(d0 * 0.25f), e1 = __expf(d1 * 0.25f);
            float e2 = __expf(d2 * 0.25f), e3 = __expf(d3 * 0.25f);
            den_[nt][0] += e0; den_[nt][1] += e1; den_[nt][2] += e2; den_[nt][3] += e3;
            oa[nt][0] += e0 * vvr[0][nt];
            oa[nt][1] += e1 * vvr[1][nt];
            oa[nt][2] += e2 * vvr[2][nt];
            oa[nt][3] += e3 * vvr[3][nt];
        }
    }
    // t = 3..5: k/v depend on i (block-uniform row i0)
#pragma unroll
    for (int t = 3; t < 6; ++t) {
        float ku[4], vu[4];
        const float* kr = kvkb + ((size_t)t * 128 + i0) * 64 + cb;
        const float* vr = kvvb + ((size_t)t * 128 + i0) * 64 + cb;
#pragma unroll
        for (int nt = 0; nt < 4; ++nt) { ku[nt] = kr[nt * 16]; vu[nt] = vr[nt * 16]; }
#pragma unroll
        for (int nt = 0; nt < 4; ++nt) {
            float d0 = qa[nt][0] * ku[nt];
            float d1 = qa[nt][1] * ku[nt];
            float d2 = qa[nt][2] * ku[nt];
            float d3 = qa[nt][3] * ku[nt];
#pragma unroll
            for (int m = 1; m < 16; m <<= 1) {
                d0 += __shfl_xor(d0, m, 64);
                d1 += __shfl_xor(d1, m, 64);
                d2 += __shfl_xor(d2, m, 64);
                d3 += __shfl_xor(d3, m, 64);
            }
            float e0 = __expf(d0 * 0.25f), e1 = __expf(d1 * 0.25f);
            float e2 = __expf(d2 * 0.25f), e3 = __expf(d3 * 0.25f);
            den_[nt][0] += e0; den_[nt][1] += e1; den_[nt][2] += e2; den_[nt][3] += e3;
            oa[nt][0] += e0 * vu[nt];
            oa[nt][1] += e1 * vu[nt];
            oa[nt][2] += e2 * vu[nt];
            oa[nt][3] += e3 * vu[nt];
        }
    }
    __syncthreads();     // all waves past q-proj; Wb free

    // ---- stage O (16 KB) into Wb; write o/den -> A-frags
#pragma unroll
    for (int i = 0; i < 4; ++i)
        *(u16x8*)(Wb + (i * 256 + tid) * 8) = *(const u16x8*)(pk + 24576 + (i * 256 + tid) * 8);
#pragma unroll
    for (int reg = 0; reg < 4; ++reg) {
        int rloc = R0 + cg * 4 + reg;
        storeA4(Ahi, rloc, cb,
                oa[0][reg] / den_[0][reg], oa[1][reg] / den_[1][reg],
                oa[2][reg] / den_[2][reg], oa[3][reg] / den_[3][reg]);
    }
    __syncthreads();

    // ---- Phase D: out-proj (Wb = O); residual (x in regs); LN2 -> A-frags
    f32x4 ao[4];
#pragma unroll
    for (int nt = 0; nt < 4; ++nt) { float bo_ = outb[nt * 16 + cb]; ao[nt] = {bo_, bo_, bo_, bo_}; }
#pragma unroll
    for (int ks = 0; ks < 2; ++ks) {
        bf16x8 ah = readFrag(Ahi, R0, lane, ks, 128, 7);
#pragma unroll
        for (int nt = 0; nt < 4; ++nt) {
            bf16x8 bh, bl;
            readB(Wb, 4096, 4, ks, nt, lane, bh, bl);
            ao[nt] = MFMA_B16(ah, bh, ao[nt]);
            ao[nt] = MFMA_B16(ah, bl, ao[nt]);
        }
    }
    float g2[4], b2v[4];
#pragma unroll
    for (int nt = 0; nt < 4; ++nt) { g2[nt] = ln2g[nt * 16 + cb]; b2v[nt] = ln2b[nt * 16 + cb]; }
    float x2[4][4];
#pragma unroll
    for (int reg = 0; reg < 4; ++reg) {
        int rloc = R0 + cg * 4 + reg;
#pragma unroll
        for (int nt = 0; nt < 4; ++nt) x2[reg][nt] = x[reg][nt] + ao[nt][reg];
        float s = x2[reg][0] + x2[reg][1] + x2[reg][2] + x2[reg][3];
#pragma unroll
        for (int m = 1; m < 16; m <<= 1) s += __shfl_xor(s, m, 64);
        float mean = s * (1.0f / 64.0f);
        float d0 = x2[reg][0] - mean, d1 = x2[reg][1] - mean, d2 = x2[reg][2] - mean, d3 = x2[reg][3] - mean;
        float sq = d0 * d0 + d1 * d1 + d2 * d2 + d3 * d3;
#pragma unroll
        for (int m = 1; m < 16; m <<= 1) sq += __shfl_xor(sq, m, 64);
        float rr = rsqrtf(sq * (1.0f / 64.0f) + 1e-5f);
        storeA4(Ahi, rloc, cb,
                d0 * rr * g2[0] + b2v[0], d1 * rr * g2[1] + b2v[1],
                d2 * rr * g2[2] + b2v[2], d3 * rr * g2[3] + b2v[3]);
    }
    __syncthreads();     // O reads done; Wb free for FFN staging

    // ---- Phase E: FFN 64->256 (gelu) ->64; 16 KB sub-chunked weight staging
    const unsigned short* pW1 = pk + 2 * OFF_W1;   // hi at 0, lo at +16384 elements
    const unsigned short* pW2 = pk + 2 * OFF_W2;
    f32x4 ya[4];
#pragma unroll
    for (int nt = 0; nt < 4; ++nt) { float by = fb2[nt * 16 + cb]; ya[nt] = {by, by, by, by}; }

#pragma unroll
    for (int cc = 0; cc < 2; ++cc) {
        f32x4 ha[8];
#pragma unroll
        for (int n8 = 0; n8 < 8; ++n8) {
            float hb = fb1[(cc * 8 + n8) * 16 + cb];
            ha[n8] = {hb, hb, hb, hb};
        }
        // W1: two 16 KB sub-chunks of 4 hidden-tiles each
#pragma unroll
        for (int h = 0; h < 2; ++h) {
#pragma unroll
            for (int it = 0; it < 4; ++it) {
                int i = it * 256 + tid;           // [0,1024) u16x8s
                int half = i >> 9, j = i & 511;
                int lt = j >> 6, lr = j & 63;     // lt = ksl*4 + n8l
                int ksl = lt >> 2, n8l = lt & 3;
                int gt = ksl * 16 + cc * 8 + h * 4 + n8l;
                *(u16x8*)(Wb + half * 4096 + (lt * 64 + lr) * 8) =
                    *(const u16x8*)(pW1 + half * 16384 + (gt * 64 + lr) * 8);
            }
            __syncthreads();
#pragma unroll
            for (int ks = 0; ks < 2; ++ks) {
                bf16x8 ah = readFrag(Ahi, R0, lane, ks, 128, 7);
#pragma unroll
                for (int n8l = 0; n8l < 4; ++n8l) {
                    bf16x8 bh, bl;
                    readB(Wb, 4096, 4, ks, n8l, lane, bh, bl);
                    ha[h * 4 + n8l] = MFMA_B16(ah, bh, ha[h * 4 + n8l]);
                    ha[h * 4 + n8l] = MFMA_B16(ah, bl, ha[h * 4 + n8l]);
                }
            }
            __syncthreads();     // W1 sub reads done
        }
        // gelu -> H frags (wave-private rows; DS in-order per wave)
#pragma unroll
        for (int reg = 0; reg < 4; ++reg) {
            int rloc = R0 + cg * 4 + reg;
            u16x8 u;
#pragma unroll
            for (int n8 = 0; n8 < 8; ++n8) {
                float h = ha[n8][reg];
                h = 0.5f * h * (1.0f + erff(h * 0.70710678118654752f));
                u[n8] = (unsigned short)rne16(h);
            }
            int bo = (rloc * 256 + cb * 16) ^ ((rloc & 15) << 4);
            *(u16x8*)((char*)Hhi + bo) = u;
        }
        // W2: two 16 KB sub-chunks of 2 K-tiles each
#pragma unroll
        for (int h2 = 0; h2 < 2; ++h2) {
#pragma unroll
            for (int it = 0; it < 4; ++it) {
                int i = it * 256 + tid;
                int half = i >> 9, j = i & 511;
                int lt = j >> 6, lr = j & 63;     // lt = ks2l*4 + nt
                int ks2l = lt >> 2, ntl = lt & 3;
                int gidx = (cc * 4 + h2 * 2 + ks2l) * 4 + ntl;
                *(u16x8*)(Wb + half * 4096 + (lt * 64 + lr) * 8) =
                    *(const u16x8*)(pW2 + half * 16384 + (gidx * 64 + lr) * 8);
            }
            __syncthreads();
#pragma unroll
            for (int ks2l = 0; ks2l < 2; ++ks2l) {
                bf16x8 ah = readFrag(Hhi, R0, lane, h2 * 2 + ks2l, 256, 15);
#pragma unroll
                for (int nt = 0; nt < 4; ++nt) {
                    bf16x8 bh, bl;
                    readB(Wb, 4096, 4, ks2l, nt, lane, bh, bl);
                    ya[nt] = MFMA_B16(ah, bh, ya[nt]);
                    ya[nt] = MFMA_B16(ah, bl, ya[nt]);
                }
            }
            __syncthreads();     // W2 sub reads done before next stage
        }
    }

    // ---- final: x2 + ffn -> Hf (wave-private rows), then coalesced float4 store
#pragma unroll
    for (int reg = 0; reg < 4; ++reg) {
        int rloc = R0 + cg * 4 + reg;
#pragma unroll
        for (int nt = 0; nt < 4; ++nt)
            Hf[rloc * 64 + nt * 16 + cb] = x2[reg][nt] + ya[nt][reg];
    }
    __syncthreads();
    {
        float4* dst4 = (float4*)(fout + ((size_t)(pi * B_ + b) * N_ + nn0) * 64);
        const float4* src4 = (const float4*)Hf;
#pragma unroll
        for (int it = 0; it < 4; ++it) {
            int i = it * 256 + tid;
            dst4[i] = src4[i];
        }
    }
}

// ---------- output transpose ----------
__global__ __launch_bounds__(256) void output_kernel(const float* __restrict__ f,
                                                     float* __restrict__ out) {
    __shared__ float tile[64][65];
    int blk = blockIdx.x;
    int ntile = blk & 255;
    int bp = blk >> 8;
    int b = bp / 3, p = bp - b * 3;
    int n0 = ntile * 64;
    int tr = threadIdx.x >> 6, tc = threadIdx.x & 63;

    const float* src = f + ((size_t)(p * B_ + b) * N_ + n0) * C_;
#pragma unroll
    for (int it = 0; it < 16; ++it) {
        int r = it * 4 + tr;
        tile[r][tc] = src[(size_t)r * C_ + tc];
    }
    __syncthreads();
    float* dst = out + (size_t)(b * 3 + p) * C_ * N_ + n0;
#pragma unroll
    for (int it = 0; it < 16; ++it) {
        int cidx = it * 4 + tr;
        dst[(size_t)cidx * N_ + tc] = tile[tc][cidx];
    }
}

extern "C" void kernel_launch(void* const* d_in, const int* in_sizes, int n_in,
                              void* d_out, int out_size, void* d_ws, size_t ws_size,
                              hipStream_t stream) {
    const float* img_feats = (const float*)d_in[0];
    const float* pts       = (const float*)d_in[1];
    const float* query     = (const float*)d_in[2];
    const float* ln1_g     = (const float*)d_in[3];
    const float* ln1_b     = (const float*)d_in[4];
    const float* ln2_g     = (const float*)d_in[5];
    const float* ln2_b     = (const float*)d_in[6];
    const float* in_w      = (const float*)d_in[7];
    const float* in_b      = (const float*)d_in[8];
    const float* out_w     = (const float*)d_in[9];
    const float* out_b     = (const float*)d_in[10];
    const float* ffn_w1    = (const float*)d_in[11];
    const float* ffn_b1    = (const float*)d_in[12];
    const float* ffn_w2    = (const float*)d_in[13];
    const float* ffn_b2    = (const float*)d_in[14];

    const size_t FEAT_SZ = (size_t)3 * B_ * N_ * C_;  // 6,291,456

    float* ws = (float*)d_ws;
    float* ftr      = ws;                                  // FTR_SZ floats
    int* counts     = (int*)(ftr + FTR_SZ);                // SEG_SZ
    int* offsets    = counts + SEG_SZ;                     // NSEG*OSTRIDE
    int* cursors    = offsets + (size_t)NSEG * OSTRIDE;    // SEG_SZ
    float4* ent     = (float4*)(cursors + SEG_SZ);         // SEG_SZ float4 (+8 pad)
    float* fA       = (float*)(ent + SEG_SZ + 8);
    float* fB       = fA + FEAT_SZ;
    unsigned short* pk_base = (unsigned short*)(fB + FEAT_SZ);
    // kv tables alias the (dead after gather_splat) counts/offsets region
    float* kvk = (float*)counts;
    float* kvv = kvk + KV_SZ;

    // ---- splat via binning + strip gather (no float atomics); query init fused
    zero_counts<<<(int)(SEG_SZ / 4 + 255) / 256, 256, 0, stream>>>((int4*)counts, (int)(SEG_SZ / 4));
    transpose_feats<<<NBV * 256, 256, 0, stream>>>(img_feats, ftr);
    bin_count<<<(NBV * N_) / 256, 256, 0, stream>>>(pts, counts);
    scan_bins<<<NSEG, 256, 0, stream>>>(counts, offsets, cursors);
    scatter_pts<<<(NBV * N_) / 256, 256, 0, stream>>>(pts, cursors, ent);
    gather_splat<<<dim3(2048, 3, B_), 512, 0, stream>>>(ftr, offsets, ent, query, fA);

    // pack weights
    for (int l = 0; l < NL_; ++l) {
        pack_layer<<<(PK_ELEMS + 255) / 256, 256, 0, stream>>>(
            in_w + (size_t)l * 3 * C_ * C_, out_w + (size_t)l * C_ * C_,
            ffn_w1 + (size_t)l * 4 * C_ * C_, ffn_w2 + (size_t)l * C_ * 4 * C_,
            pk_base + (size_t)l * LAYER_PK);
    }

    dim3 pgrid((B_ * N_) / 64, 3);
    for (int l = 0; l < NL_; ++l) {
        const float* fin = (l == 0) ? fA : fB;
        float* fout      = (l == 0) ? fB : fA;
        ctx_kv<<<144, 256, 0, stream>>>(fin, ln1_g + l * C_, ln1_b + l * C_,
                                        in_w + (size_t)l * 3 * C_ * C_, in_b + l * 3 * C_,
                                        kvk, kvv);
        plane_mfma<<<pgrid, 256, 0, stream>>>(
            fin, fout, pk_base + (size_t)l * LAYER_PK, kvk, kvv,
            ln1_g + l * C_, ln1_b + l * C_,
            ln2_g + l * C_, ln2_b + l * C_,
            in_b + l * 3 * C_, out_b + l * C_,
            ffn_b1 + l * 4 * C_, ffn_b2 + l * C_);
    }

    output_kernel<<<B_ * 3 * (N_ / 64), 256, 0, stream>>>(fA, (float*)d_out);
}

// Round 20
// 350.743 us; speedup vs baseline: 1.0721x; 1.0721x over previous
//
#include <hip/hip_runtime.h>
#include <math.h>

constexpr int R_ = 128, C_ = 64, NL_ = 2, B_ = 2, V_ = 4;
constexpr int N_ = R_ * R_;          // 16384
constexpr int T_ = 6;

typedef __attribute__((ext_vector_type(8))) short bf16x8;
typedef __attribute__((ext_vector_type(4))) float f32x4;
typedef __attribute__((ext_vector_type(4))) unsigned short u16x4;
typedef __attribute__((ext_vector_type(8))) unsigned short u16x8;
typedef __attribute__((ext_vector_type(2))) __fp16 h2;

#define MFMA_B16(a, b, c) __builtin_amdgcn_mfma_f32_16x16x32_bf16((a), (b), (c), 0, 0, 0)

// packed-weight element offsets (per layer, in elements)
constexpr int OFF_O = 12288, OFF_W1 = 16384, OFF_W2 = 32768;
constexpr int PK_ELEMS = 49152;
constexpr int LAYER_PK = 2 * PK_ELEMS;   // ushorts per layer (hi+lo)

// splat-path sizes
constexpr int NBV = B_ * V_;                       // 8
constexpr size_t FTR_SZ = (size_t)NBV * N_ * C_;   // 8,388,608 floats
constexpr int NSEG = 3 * NBV;                      // 24 segments
constexpr size_t SEG_SZ = (size_t)NSEG * N_;       // 393,216 ints
constexpr int OSTRIDE = N_ + 128;                  // offsets stride (sentinel pad)
constexpr size_t KV_SZ = (size_t)3 * B_ * T_ * 128 * 64;   // 294,912 floats

// ---------- helpers ----------
__device__ inline unsigned rne16(float x) {
    unsigned b = __float_as_uint(x);
    return (b + 0x7fffu + ((b >> 16) & 1u)) >> 16;
}

__device__ inline float wsum(float v) {
#pragma unroll
    for (int m = 1; m < 64; m <<= 1) v += __shfl_xor(v, m, 64);
    return v;
}

__device__ inline float lnorm(float v, float g, float b) {
    float m = wsum(v) * (1.f / 64.f);
    float d = v - m;
    float var = wsum(d * d) * (1.f / 64.f);
    return d * rsqrtf(var + 1e-5f) * g + b;
}

// stage a 64x64 row-major fp32 matrix into LDS buf[c*68 + u]
__device__ inline void stageW(const float* __restrict__ W, float* buf, int tid) {
#pragma unroll
    for (int it = 0; it < 4; ++it) {
        int idx4 = it * 256 + tid;
        int r = idx4 >> 4, u4 = idx4 & 15;
        float4 v = ((const float4*)W)[idx4];
        *(float4*)&buf[r * 68 + u4 * 4] = v;
    }
}

// read A-fragment (16x32 bf16) for wave's M-tile from swizzled LDS
__device__ inline bf16x8 readFrag(const unsigned short* base, int rowBase, int lane,
                                  int ks, int rowStrideB, int swzMask) {
    int rowloc = rowBase + (lane & 15);
    int off = rowloc * rowStrideB + ks * 64 + ((lane >> 4) & 3) * 16;
    off ^= ((rowloc & swzMask) << 4);
    return *(const bf16x8*)((const char*)base + off);
}

// store 4 bf16-hi values (K-permuted: p = cb*4+nt) as one 8B write
__device__ inline void storeA4(unsigned short* base, int rloc, int cb,
                               float v0, float v1, float v2, float v3) {
    u16x4 u;
    u[0] = (unsigned short)rne16(v0);
    u[1] = (unsigned short)rne16(v1);
    u[2] = (unsigned short)rne16(v2);
    u[3] = (unsigned short)rne16(v3);
    int bo = (rloc * 128 + cb * 8) ^ ((rloc & 7) << 4);
    *(u16x4*)((char*)base + bo) = u;
}

// load B-fragment pair (hi,lo) from a weight table (global or LDS)
__device__ inline void readB(const unsigned short* matHi, int E, int NTm, int ks, int nt,
                             int lane, bf16x8& bh, bf16x8& bl) {
    int off = (((ks * NTm + nt) << 6) + lane) << 3;
    bh = *(const bf16x8*)(matHi + off);
    bl = *(const bf16x8*)(matHi + E + off);
}

// ---------- pack all weights of one layer (K-permuted, split hi/lo) ----------
__global__ __launch_bounds__(256) void pack_layer(const float* __restrict__ iw,
                                                  const float* __restrict__ ow,
                                                  const float* __restrict__ w1,
                                                  const float* __restrict__ w2,
                                                  unsigned short* __restrict__ pk) {
    int idx = blockIdx.x * 256 + threadIdx.x;
    if (idx >= PK_ELEMS) return;
    const float* W;
    int O, K, base, mode, lidx;
    if (idx < 12288)      { int m = idx >> 12; lidx = idx & 4095; W = iw + m * 4096; O = 64;  K = 64;  base = m * 4096; mode = 0; }
    else if (idx < 16384) { lidx = idx - 12288; W = ow; O = 64;  K = 64;  base = OFF_O;  mode = 0; }
    else if (idx < 32768) { lidx = idx - 16384; W = w1; O = 256; K = 64;  base = OFF_W1; mode = 0; }
    else                  { lidx = idx - 32768; W = w2; O = 64;  K = 256; base = OFF_W2; mode = 1; }
    int j = lidx & 7, l = (lidx >> 3) & 63, rem = lidx >> 9;
    int NTm = O >> 4;
    int nt = rem & (NTm - 1), ks = rem / NTm;
    int kfrag = ks * 32 + ((l >> 4) & 3) * 8 + j;
    int k;
    if (mode == 0) { int p = kfrag & 63; k = (p & 3) * 16 + (p >> 2); }
    else { int cc = kfrag >> 7; int pl = kfrag & 127; k = (cc * 8 + (pl & 7)) * 16 + (pl >> 3); }
    int o = nt * 16 + (l & 15);
    float w = W[(size_t)o * K + k];
    unsigned hb = rne16(w);
    float hf = __uint_as_float(hb << 16);
    unsigned lb = rne16(w - hf);
    int E = O * K;
    pk[2 * base + lidx] = (unsigned short)hb;
    pk[2 * base + E + lidx] = (unsigned short)lb;
}

// ---------- zero bin counts ----------
__global__ __launch_bounds__(256) void zero_counts(int4* __restrict__ p, int n4) {
    int i = blockIdx.x * 256 + threadIdx.x;
    if (i < n4) p[i] = make_int4(0, 0, 0, 0);
}

// ---------- transpose features: [bv][c][n] -> [bv][n][c] ----------
__global__ __launch_bounds__(256) void transpose_feats(const float* __restrict__ src,
                                                       float* __restrict__ dst) {
    __shared__ float tile[64][65];
    int blk = blockIdx.x;             // NBV * 256
    int ntile = blk & 255;
    int bv = blk >> 8;
    int n0 = ntile * 64;
    int tr = threadIdx.x >> 6, tc = threadIdx.x & 63;
    const float* s = src + (size_t)bv * C_ * N_;
#pragma unroll
    for (int it = 0; it < 16; ++it) {
        int c = it * 4 + tr;
        tile[c][tc] = s[(size_t)c * N_ + n0 + tc];
    }
    __syncthreads();
    float* d = dst + ((size_t)bv * N_ + n0) * C_;
#pragma unroll
    for (int it = 0; it < 16; ++it) {
        int r = it * 4 + tr;
        d[(size_t)r * C_ + tc] = tile[tc][r];
    }
}

// ---------- bin count ----------
__global__ __launch_bounds__(256) void bin_count(const float* __restrict__ pts,
                                                 int* __restrict__ counts) {
    int idx = blockIdx.x * 256 + threadIdx.x;     // [0, NBV*N)
    if (idx >= NBV * N_) return;
    int bv = idx >> 14;
    const float* p = pts + (size_t)idx * 3;
    float px = p[0], py = p[1], pz = p[2];
    const float HI = (float)(127.0 - 1e-5);
    float gx = fminf(fmaxf((px + 1.0f) * 127.0f / 2.0f, 0.0f), HI);
    float gy = fminf(fmaxf((py + 1.0f) * 127.0f / 2.0f, 0.0f), HI);
    float gz = fminf(fmaxf((pz + 1.0f) * 127.0f / 2.0f, 0.0f), HI);
    int x0 = (int)gx, y0 = (int)gy, z0 = (int)gz;
    atomicAdd(&counts[(0 * NBV + bv) * N_ + x0 * R_ + y0], 1);
    atomicAdd(&counts[(1 * NBV + bv) * N_ + x0 * R_ + z0], 1);
    atomicAdd(&counts[(2 * NBV + bv) * N_ + y0 * R_ + z0], 1);
}

// ---------- per-segment exclusive scan (16384 bins each) + sentinel pad ----------
__global__ __launch_bounds__(256) void scan_bins(const int* __restrict__ counts,
                                                 int* __restrict__ offsets,
                                                 int* __restrict__ cursors) {
    __shared__ int part[256];
    int seg = blockIdx.x;             // 24
    int t = threadIdx.x;
    const int* c = counts + (size_t)seg * N_;
    int sum = 0;
    for (int i = 0; i < 64; ++i) sum += c[t * 64 + i];
    part[t] = sum;
    __syncthreads();
    if (t == 0) {
        int run = 0;
        for (int i = 0; i < 256; ++i) { int v = part[i]; part[i] = run; run += v; }
    }
    __syncthreads();
    int run = part[t];
    int* o = offsets + (size_t)seg * OSTRIDE;
    int* cu = cursors + (size_t)seg * N_;
    for (int i = 0; i < 64; ++i) {
        o[t * 64 + i] = run;
        cu[t * 64 + i] = run;
        run += c[t * 64 + i];
    }
    if (t < 128) o[N_ + t] = N_;      // sentinel: total per segment == N_
}

// ---------- scatter records (n, fp16 weight pairs) into bin-sorted lists ----------
__global__ __launch_bounds__(256) void scatter_pts(const float* __restrict__ pts,
                                                   int* __restrict__ cursors,
                                                   float4* __restrict__ ent) {
    int idx = blockIdx.x * 256 + threadIdx.x;
    if (idx >= NBV * N_) return;
    int bv = idx >> 14, n = idx & (N_ - 1);
    const float* p = pts + (size_t)idx * 3;
    float px = p[0], py = p[1], pz = p[2];
    const float HI = (float)(127.0 - 1e-5);
    float gx = fminf(fmaxf((px + 1.0f) * 127.0f / 2.0f, 0.0f), HI);
    float gy = fminf(fmaxf((py + 1.0f) * 127.0f / 2.0f, 0.0f), HI);
    float gz = fminf(fmaxf((pz + 1.0f) * 127.0f / 2.0f, 0.0f), HI);
    int x0 = (int)gx, y0 = (int)gy, z0 = (int)gz;
    float wx = gx - (float)x0, wy = gy - (float)y0, wz = gz - (float)z0;
    float ax = 1.f - wx, ay = 1.f - wy, az = 1.f - wz;
    float4 e;
    e.x = __uint_as_float((unsigned)n);
    e.w = 0.f;
    int s0 = 0 * NBV + bv, s1 = 1 * NBV + bv, s2 = 2 * NBV + bv;
    // plane0 (bin row x0, col y0): dr0 -> {w000, w010}; dr1 -> {w100, w110}
    {
        h2 a = __builtin_amdgcn_cvt_pkrtz(ax * ay * az, ax * wy * az);
        h2 bq = __builtin_amdgcn_cvt_pkrtz(wx * ay * az, wx * wy * az);
        e.y = *(float*)&a; e.z = *(float*)&bq;
        int p0 = atomicAdd(&cursors[(size_t)s0 * N_ + x0 * R_ + y0], 1);
        ent[(size_t)s0 * N_ + p0] = e;
    }
    // plane1 (bin row x0, col z0): dr0 -> {w000, w001}; dr1 -> {w100, w111}
    {
        h2 a = __builtin_amdgcn_cvt_pkrtz(ax * ay * az, ax * ay * wz);
        h2 bq = __builtin_amdgcn_cvt_pkrtz(wx * ay * az, wx * wy * wz);
        e.y = *(float*)&a; e.z = *(float*)&bq;
        int p1 = atomicAdd(&cursors[(size_t)s1 * N_ + x0 * R_ + z0], 1);
        ent[(size_t)s1 * N_ + p1] = e;
    }
    // plane2 (bin row y0, col z0): dr0 -> {w000, w001}; dr1 -> {w010, w111}
    {
        h2 a = __builtin_amdgcn_cvt_pkrtz(ax * ay * az, ax * ay * wz);
        h2 bq = __builtin_amdgcn_cvt_pkrtz(ax * wy * az, wx * wy * wz);
        e.y = *(float*)&a; e.z = *(float*)&bq;
        int p2 = atomicAdd(&cursors[(size_t)s2 * N_ + y0 * R_ + z0], 1);
        ent[(size_t)s2 * N_ + p2] = e;
    }
}

// ---------- gather splat: block = 8-cell strip; wave = (view, bin-row) ----------
// register accumulators (compile-time j), fp16 precomputed weights, fused query init
__global__ __launch_bounds__(512) void gather_splat(
    const float* __restrict__ ftr, const int* __restrict__ offsets,
    const float4* __restrict__ ent, const float* __restrict__ query,
    float* __restrict__ f0) {
    __shared__ float sfacc[8][8][64];
    __shared__ float swsum[8][8];
    int wid = threadIdx.x >> 6, lane = threadIdx.x & 63;
    int v = wid >> 1, dr = wid & 1;
    int strip = blockIdx.x;                   // [0, 2048)
    int pi = blockIdx.y, b = blockIdx.z;
    int a = strip >> 4;                       // cell row
    int c0 = (strip & 15) << 3;               // first cell col of strip

    int bv = b * V_ + v;
    int seg = pi * NBV + bv;
    const int* ob = offsets + (size_t)seg * OSTRIDE;
    const float4* eb = ent + (size_t)seg * N_;
    const float* fbase = ftr + (size_t)bv * N_ * C_ + lane;
    float facc[8], wsum_[8];
#pragma unroll
    for (int k = 0; k < 8; ++k) { facc[k] = 0.f; wsum_[k] = 0.f; }

    int ba = a - dr;
    if (ba >= 0) {
        int rowbase = ba * R_ + c0 - 1;
        int o[10];
#pragma unroll
        for (int jj = 0; jj < 10; ++jj)
            o[jj] = ob[max(rowbase + jj, 0)];
#pragma unroll
        for (int j = 0; j < 9; ++j) {
            if (j == 0 && c0 == 0) continue;    // bin col -1 doesn't exist
            int e = o[j + 1];
            for (int i = o[j]; i < e; ++i) {
                float4 r = eb[i];
                int n = (int)(__float_as_uint(r.x) & 16383u);
                float pr = dr ? r.z : r.y;
                h2 ph = *(h2*)&pr;
                float w0 = (float)ph[0], w1 = (float)ph[1];
                float f = fbase[(size_t)n * C_];
                if (j > 0) { facc[j - 1] += w0 * f; wsum_[j - 1] += w0; }
                if (j < 8) { facc[j] += w1 * f; wsum_[j] += w1; }
            }
        }
    }
#pragma unroll
    for (int k = 0; k < 8; ++k) sfacc[wid][k][lane] = facc[k];
    if (lane == 0) {
#pragma unroll
        for (int k = 0; k < 8; ++k) swsum[wid][k] = wsum_[k];
    }
    __syncthreads();

    // combine: wave wid handles cell k = wid (sum dr pair per view, then normalize)
    int k = wid;
    int cell = a * R_ + c0 + k;
    float tot = 0.f;
#pragma unroll
    for (int v2 = 0; v2 < 4; ++v2) {
        float fa = sfacc[v2 * 2][k][lane] + sfacc[v2 * 2 + 1][k][lane];
        float wsv = swsum[v2 * 2][k] + swsum[v2 * 2 + 1][k];
        tot += fa / fmaxf(wsv, 1e-8f);
    }
    float qv = query[((size_t)pi * N_ + cell) * C_ + lane];
    f0[(((size_t)(pi * B_ + b)) * N_ + cell) * C_ + lane] = qv + 0.25f * tot;
}

// ---------- ctx k/v table: 4608 rows = (pi, b, t, pos) ----------
__global__ __launch_bounds__(256) void ctx_kv(
    const float* __restrict__ fin,
    const float* __restrict__ ln1g, const float* __restrict__ ln1b,
    const float* __restrict__ inw, const float* __restrict__ inb,
    float* __restrict__ kvk, float* __restrict__ kvv) {
    __shared__ float s_wk[64 * 68];
    __shared__ float s_wv[64 * 68];
    __shared__ float s_act[32 * 68];
    int tid = threadIdx.x, wid = tid >> 6, lane = tid & 63;
    stageW(inw + 4096, s_wk, tid);     // Wk
    stageW(inw + 8192, s_wv, tid);     // Wv

    int rid0 = blockIdx.x * 32 + wid * 8;
    int seg = rid0 >> 7;               // (pi*2+b)*6 + t
    int pos0 = rid0 & 127;
    int t = seg % 6;
    int pib = seg / 6;
    int pi = pib >> 1, b = pib & 1;
    int khalf = (t < 3) ? t : t - 3;
    float sk = (float)(khalf - 1);
    bool tl = t < 3;
    int io;
    if (pi == 0) io = tl ? 1 : 2;
    else if (pi == 1) io = tl ? 0 : 2;
    else io = tl ? 0 : 1;
    const float* Fio = fin + (size_t)(io * B_ + b) * N_ * 64;
    float g1 = ln1g[lane], b1 = ln1b[lane];

#pragma unroll
    for (int rr = 0; rr < 8; ++rr) {
        int pos = pos0 + rr;
        float lp = -1.0f + (2.0f * (float)pos) / 127.0f;
        float caf, cbf;
        if (pi == 0) { caf = lp; cbf = sk; }
        else if (pi == 1) { if (tl) { caf = lp; cbf = sk; } else { caf = sk; cbf = lp; } }
        else { caf = sk; cbf = lp; }
        float ua = fminf(fmaxf((caf * 0.5f + 0.5f) * 127.0f, 0.0f), 127.0f);
        float ub = fminf(fmaxf((cbf * 0.5f + 0.5f) * 127.0f, 0.0f), 127.0f);
        float gxp = fminf(fmaxf(((ua + 1.0f) * 0.5f) * 127.0f, 0.0f), 127.0f);
        float gyp = fminf(fmaxf(((ub + 1.0f) * 0.5f) * 127.0f, 0.0f), 127.0f);
        int xx0 = (int)gxp, yy0 = (int)gyp;
        int xx1 = xx0 + 1 < 128 ? xx0 + 1 : 127;
        int yy1 = yy0 + 1 < 128 ? yy0 + 1 : 127;
        float wx = gxp - (float)xx0, wy = gyp - (float)yy0;
        float v00 = Fio[(size_t)(yy0 * R_ + xx0) * 64 + lane];
        float v01 = Fio[(size_t)(yy0 * R_ + xx1) * 64 + lane];
        float v10 = Fio[(size_t)(yy1 * R_ + xx0) * 64 + lane];
        float v11 = Fio[(size_t)(yy1 * R_ + xx1) * 64 + lane];
        float cv = (1.0f - wy) * ((1.0f - wx) * v00 + wx * v01) +
                   wy * ((1.0f - wx) * v10 + wx * v11);
        s_act[(wid * 8 + rr) * 68 + lane] = lnorm(cv, g1, b1);
    }
    __syncthreads();

    float kk[8], vv[8];
    float bk = inb[64 + lane], bv = inb[128 + lane];
#pragma unroll
    for (int rr = 0; rr < 8; ++rr) { kk[rr] = bk; vv[rr] = bv; }
    const float* wrk = s_wk + lane * 68;
    const float* wrv = s_wv + lane * 68;
#pragma unroll 4
    for (int g = 0; g < 16; ++g) {
        float4 wk4 = *(const float4*)(wrk + g * 4);
        float4 wv4 = *(const float4*)(wrv + g * 4);
#pragma unroll
        for (int rr = 0; rr < 8; ++rr) {
            float4 xv = *(const float4*)(s_act + (wid * 8 + rr) * 68 + g * 4);
            kk[rr] = fmaf(xv.x, wk4.x, fmaf(xv.y, wk4.y, fmaf(xv.z, wk4.z, fmaf(xv.w, wk4.w, kk[rr]))));
            vv[rr] = fmaf(xv.x, wv4.x, fmaf(xv.y, wv4.y, fmaf(xv.z, wv4.z, fmaf(xv.w, wv4.w, vv[rr]))));
        }
    }
#pragma unroll
    for (int rr = 0; rr < 8; ++rr) {
        size_t o = ((size_t)seg * 128 + pos0 + rr) * 64 + lane;
        kvk[o] = kk[rr];
        kvv[o] = vv[rr];
    }
}

// ---------- fused per-plane transformer layer (MFMA, precomputed k/v) ----------
__global__ __launch_bounds__(256, 2) void plane_mfma(
    const float* __restrict__ fin, float* __restrict__ fout,
    const unsigned short* __restrict__ pk,
    const float* __restrict__ kvk, const float* __restrict__ kvv,
    const float* __restrict__ ln1g, const float* __restrict__ ln1b,
    const float* __restrict__ ln2g, const float* __restrict__ ln2b,
    const float* __restrict__ inb, const float* __restrict__ outb,
    const float* __restrict__ fb1, const float* __restrict__ fb2) {
    __shared__ __attribute__((aligned(16))) unsigned short Wb[16384];  // 32 KB weight stage
    __shared__ __attribute__((aligned(16))) unsigned short Ahi[4096];  // 8 KB A-frags
    __shared__ __attribute__((aligned(16))) float Hf[4096];            // 16 KB H-frags / out stage
    unsigned short* Hhi = (unsigned short*)Hf;

    const int tid = threadIdx.x;
    const int wid = tid >> 6, lane = tid & 63;
    const int cg = lane >> 4, cb = lane & 15;
    const int pi = blockIdx.y;
    const int R0 = wid * 16;
    const int rowbase = blockIdx.x * 64;
    const int b = rowbase >> 14;
    const int nn0 = rowbase & (N_ - 1);
    const int i0 = nn0 >> 7, j0 = nn0 & 127;

    // ---- stage Q (16 KB) into Wb[0:8192] AND O (16 KB) into Wb[8192:16384]
#pragma unroll
    for (int i = 0; i < 4; ++i)
        *(u16x8*)(Wb + (i * 256 + tid) * 8) = *(const u16x8*)(pk + (i * 256 + tid) * 8);
#pragma unroll
    for (int i = 0; i < 4; ++i)
        *(u16x8*)(Wb + 8192 + (i * 256 + tid) * 8) = *(const u16x8*)(pk + 24576 + (i * 256 + tid) * 8);

    float g1[4], b1v[4];
#pragma unroll
    for (int nt = 0; nt < 4; ++nt) { g1[nt] = ln1g[nt * 16 + cb]; b1v[nt] = ln1b[nt * 16 + cb]; }

    // ---- Phase A: load x (kept in regs), LN1 -> A-frags (wave-private LDS rows)
    float x[4][4];
    const float* finp = fin + ((size_t)(pi * B_ + b) * N_ + nn0) * 64;
#pragma unroll
    for (int reg = 0; reg < 4; ++reg) {
        int rloc = R0 + cg * 4 + reg;
#pragma unroll
        for (int nt = 0; nt < 4; ++nt) x[reg][nt] = finp[(size_t)rloc * 64 + nt * 16 + cb];
        float s = x[reg][0] + x[reg][1] + x[reg][2] + x[reg][3];
#pragma unroll
        for (int m = 1; m < 16; m <<= 1) s += __shfl_xor(s, m, 64);
        float mean = s * (1.0f / 64.0f);
        float d0 = x[reg][0] - mean, d1 = x[reg][1] - mean, d2 = x[reg][2] - mean, d3 = x[reg][3] - mean;
        float sq = d0 * d0 + d1 * d1 + d2 * d2 + d3 * d3;
#pragma unroll
        for (int m = 1; m < 16; m <<= 1) sq += __shfl_xor(sq, m, 64);
        float rr = rsqrtf(sq * (1.0f / 64.0f) + 1e-5f);
        storeA4(Ahi, rloc, cb,
                d0 * rr * g1[0] + b1v[0], d1 * rr * g1[1] + b1v[1],
                d2 * rr * g1[2] + b1v[2], d3 * rr * g1[3] + b1v[3]);
    }
    __syncthreads();     // Q+O staged; LN1 A-frags ready

    // ---- Phase B: q = xn @ Wq^T + bq  (Wb[0:8192] = Q)
    f32x4 qa[4];
#pragma unroll
    for (int nt = 0; nt < 4; ++nt) { float bq = inb[nt * 16 + cb]; qa[nt] = {bq, bq, bq, bq}; }
#pragma unroll
    for (int ks = 0; ks < 2; ++ks) {
        bf16x8 ah = readFrag(Ahi, R0, lane, ks, 128, 7);
#pragma unroll
        for (int nt = 0; nt < 4; ++nt) {
            bf16x8 bh, bl;
            readB(Wb, 4096, 4, ks, nt, lane, bh, bl);
            qa[nt] = MFMA_B16(ah, bh, qa[nt]);
            qa[nt] = MFMA_B16(ah, bl, qa[nt]);
        }
    }

    // ---- Phase C: attention with precomputed k/v (no barriers, no LDS)
    const float* kvkb = kvk + (size_t)((pi * 2 + b) * 6) * 128 * 64;
    const float* kvvb = kvv + (size_t)((pi * 2 + b) * 6) * 128 * 64;
    float den_[4][4];
    f32x4 oa[4];
#pragma unroll
    for (int nt = 0; nt < 4; ++nt) {
        oa[nt] = {0.f, 0.f, 0.f, 0.f};
#pragma unroll
        for (int reg = 0; reg < 4; ++reg) den_[nt][reg] = 0.f;
    }

    // t = 0..2: k/v depend on j (per-row)
#pragma unroll
    for (int t = 0; t < 3; ++t) {
        float kvr[4][4], vvr[4][4];
#pragma unroll
        for (int reg = 0; reg < 4; ++reg) {
            int pos = j0 + R0 + cg * 4 + reg;
            const float* kr = kvkb + ((size_t)t * 128 + pos) * 64 + cb;
            const float* vr = kvvb + ((size_t)t * 128 + pos) * 64 + cb;
#pragma unroll
            for (int nt = 0; nt < 4; ++nt) {
                kvr[reg][nt] = kr[nt * 16];
                vvr[reg][nt] = vr[nt * 16];
            }
        }
#pragma unroll
        for (int nt = 0; nt < 4; ++nt) {
            float d0 = qa[nt][0] * kvr[0][nt];
            float d1 = qa[nt][1] * kvr[1][nt];
            float d2 = qa[nt][2] * kvr[2][nt];
            float d3 = qa[nt][3] * kvr[3][nt];
#pragma unroll
            for (int m = 1; m < 16; m <<= 1) {
                d0 += __shfl_xor(d0, m, 64);
                d1 += __shfl_xor(d1, m, 64);
                d2 += __shfl_xor(d2, m, 64);
                d3 += __shfl_xor(d3, m, 64);
            }
            float e0 = __expf(d0 * 0.25f), e1 = __expf(d1 * 0.25f);
            float e2 = __expf(d2 * 0.25f), e3 = __expf(d3 * 0.25f);
            den_[nt][0] += e0; den_[nt][1] += e1; den_[nt][2] += e2; den_[nt][3] += e3;
            oa[nt][0] += e0 * vvr[0][nt];
            oa[nt][1] += e1 * vvr[1][nt];
            oa[nt][2] += e2 * vvr[2][nt];
            oa[nt][3] += e3 * vvr[3][nt];
        }
    }
    // t = 3..5: k/v depend on i (block-uniform row i0)
#pragma unroll
    for (int t = 3; t < 6; ++t) {
        float ku[4], vu[4];
        const float* kr = kvkb + ((size_t)t * 128 + i0) * 64 + cb;
        const float* vr = kvvb + ((size_t)t * 128 + i0) * 64 + cb;
#pragma unroll
        for (int nt = 0; nt < 4; ++nt) { ku[nt] = kr[nt * 16]; vu[nt] = vr[nt * 16]; }
#pragma unroll
        for (int nt = 0; nt < 4; ++nt) {
            float d0 = qa[nt][0] * ku[nt];
            float d1 = qa[nt][1] * ku[nt];
            float d2 = qa[nt][2] * ku[nt];
            float d3 = qa[nt][3] * ku[nt];
#pragma unroll
            for (int m = 1; m < 16; m <<= 1) {
                d0 += __shfl_xor(d0, m, 64);
                d1 += __shfl_xor(d1, m, 64);
                d2 += __shfl_xor(d2, m, 64);
                d3 += __shfl_xor(d3, m, 64);
            }
            float e0 = __expf(d0 * 0.25f), e1 = __expf(d1 * 0.25f);
            float e2 = __expf(d2 * 0.25f), e3 = __expf(d3 * 0.25f);
            den_[nt][0] += e0; den_[nt][1] += e1; den_[nt][2] += e2; den_[nt][3] += e3;
            oa[nt][0] += e0 * vu[nt];
            oa[nt][1] += e1 * vu[nt];
            oa[nt][2] += e2 * vu[nt];
            oa[nt][3] += e3 * vu[nt];
        }
    }

    // ---- write o/den -> A-frags (wave-private rows; DS in-order per wave, no barrier)
#pragma unroll
    for (int reg = 0; reg < 4; ++reg) {
        int rloc = R0 + cg * 4 + reg;
        storeA4(Ahi, rloc, cb,
                oa[0][reg] / den_[0][reg], oa[1][reg] / den_[1][reg],
                oa[2][reg] / den_[2][reg], oa[3][reg] / den_[3][reg]);
    }

    // ---- Phase D: out-proj (Wb[8192:] = O, pre-staged); residual; LN2 -> A-frags
    f32x4 ao[4];
#pragma unroll
    for (int nt = 0; nt < 4; ++nt) { float bo_ = outb[nt * 16 + cb]; ao[nt] = {bo_, bo_, bo_, bo_}; }
#pragma unroll
    for (int ks = 0; ks < 2; ++ks) {
        bf16x8 ah = readFrag(Ahi, R0, lane, ks, 128, 7);
#pragma unroll
        for (int nt = 0; nt < 4; ++nt) {
            bf16x8 bh, bl;
            readB(Wb + 8192, 4096, 4, ks, nt, lane, bh, bl);
            ao[nt] = MFMA_B16(ah, bh, ao[nt]);
            ao[nt] = MFMA_B16(ah, bl, ao[nt]);
        }
    }
    float g2[4], b2v[4];
#pragma unroll
    for (int nt = 0; nt < 4; ++nt) { g2[nt] = ln2g[nt * 16 + cb]; b2v[nt] = ln2b[nt * 16 + cb]; }
    float x2[4][4];
#pragma unroll
    for (int reg = 0; reg < 4; ++reg) {
        int rloc = R0 + cg * 4 + reg;
#pragma unroll
        for (int nt = 0; nt < 4; ++nt) x2[reg][nt] = x[reg][nt] + ao[nt][reg];
        float s = x2[reg][0] + x2[reg][1] + x2[reg][2] + x2[reg][3];
#pragma unroll
        for (int m = 1; m < 16; m <<= 1) s += __shfl_xor(s, m, 64);
        float mean = s * (1.0f / 64.0f);
        float d0 = x2[reg][0] - mean, d1 = x2[reg][1] - mean, d2 = x2[reg][2] - mean, d3 = x2[reg][3] - mean;
        float sq = d0 * d0 + d1 * d1 + d2 * d2 + d3 * d3;
#pragma unroll
        for (int m = 1; m < 16; m <<= 1) sq += __shfl_xor(sq, m, 64);
        float rr = rsqrtf(sq * (1.0f / 64.0f) + 1e-5f);
        storeA4(Ahi, rloc, cb,
                d0 * rr * g2[0] + b2v[0], d1 * rr * g2[1] + b2v[1],
                d2 * rr * g2[2] + b2v[2], d3 * rr * g2[3] + b2v[3]);
    }
    __syncthreads();     // Q/O reads done everywhere; Wb free for FFN staging

    // ---- Phase E: FFN 64->256 (gelu) ->64, 2 chunks of 128 hidden, staged weights
    const unsigned short* pW1 = pk + 2 * OFF_W1;
    const unsigned short* pW2 = pk + 2 * OFF_W2;
    f32x4 ya[4];
#pragma unroll
    for (int nt = 0; nt < 4; ++nt) { float by = fb2[nt * 16 + cb]; ya[nt] = {by, by, by, by}; }

#pragma unroll
    for (int cc = 0; cc < 2; ++cc) {
        // stage W1 chunk cc (32 KB): global tile gt=ks*16+cc*8+n8 -> lds tile lt=ks*8+n8
#pragma unroll
        for (int it = 0; it < 8; ++it) {
            int i = it * 256 + tid;
            int half = i >> 10, j = i & 1023;
            int lt = j >> 6, lr = j & 63;
            int ksl = lt >> 3, n8 = lt & 7;
            int gt = ksl * 16 + cc * 8 + n8;
            *(u16x8*)(Wb + half * 8192 + (lt * 64 + lr) * 8) =
                *(const u16x8*)(pW1 + half * 16384 + (gt * 64 + lr) * 8);
        }
        __syncthreads();

        f32x4 ha[8];
#pragma unroll
        for (int n8 = 0; n8 < 8; ++n8) {
            float hb = fb1[(cc * 8 + n8) * 16 + cb];
            ha[n8] = {hb, hb, hb, hb};
        }
#pragma unroll
        for (int ks = 0; ks < 2; ++ks) {
            bf16x8 ah = readFrag(Ahi, R0, lane, ks, 128, 7);
#pragma unroll
            for (int n8 = 0; n8 < 8; ++n8) {
                bf16x8 bh, bl;
                readB(Wb, 8192, 8, ks, n8, lane, bh, bl);
                ha[n8] = MFMA_B16(ah, bh, ha[n8]);
                ha[n8] = MFMA_B16(ah, bl, ha[n8]);
            }
        }
        // gelu -> H frags (wave-private rows)
#pragma unroll
        for (int reg = 0; reg < 4; ++reg) {
            int rloc = R0 + cg * 4 + reg;
            u16x8 u;
#pragma unroll
            for (int n8 = 0; n8 < 8; ++n8) {
                float h = ha[n8][reg];
                h = 0.5f * h * (1.0f + erff(h * 0.70710678118654752f));
                u[n8] = (unsigned short)rne16(h);
            }
            int bo = (rloc * 256 + cb * 16) ^ ((rloc & 15) << 4);
            *(u16x8*)((char*)Hhi + bo) = u;
        }
        __syncthreads();     // W1 reads done

        // stage W2 chunk cc (32 KB): contiguous tiles [cc*16, cc*16+16)
#pragma unroll
        for (int it = 0; it < 8; ++it) {
            int i = it * 256 + tid;
            int half = i >> 10, j = i & 1023;
            *(u16x8*)(Wb + half * 8192 + j * 8) =
                *(const u16x8*)(pW2 + half * 16384 + cc * 8192 + j * 8);
        }
        __syncthreads();

#pragma unroll
        for (int ks2 = 0; ks2 < 4; ++ks2) {
            bf16x8 ah = readFrag(Hhi, R0, lane, ks2, 256, 15);
#pragma unroll
            for (int nt = 0; nt < 4; ++nt) {
                bf16x8 bh, bl;
                readB(Wb, 8192, 4, ks2, nt, lane, bh, bl);
                ya[nt] = MFMA_B16(ah, bh, ya[nt]);
                ya[nt] = MFMA_B16(ah, bl, ya[nt]);
            }
        }
        __syncthreads();     // W2 reads done before next chunk restage
    }

    // ---- final: x2 + ffn -> Hf (wave-private rows), then coalesced float4 store
#pragma unroll
    for (int reg = 0; reg < 4; ++reg) {
        int rloc = R0 + cg * 4 + reg;
#pragma unroll
        for (int nt = 0; nt < 4; ++nt)
            Hf[rloc * 64 + nt * 16 + cb] = x2[reg][nt] + ya[nt][reg];
    }
    __syncthreads();
    {
        float4* dst4 = (float4*)(fout + ((size_t)(pi * B_ + b) * N_ + nn0) * 64);
        const float4* src4 = (const float4*)Hf;
#pragma unroll
        for (int it = 0; it < 4; ++it) {
            int i = it * 256 + tid;
            dst4[i] = src4[i];
        }
    }
}

// ---------- output transpose ----------
__global__ __launch_bounds__(256) void output_kernel(const float* __restrict__ f,
                                                     float* __restrict__ out) {
    __shared__ float tile[64][65];
    int blk = blockIdx.x;
    int ntile = blk & 255;
    int bp = blk >> 8;
    int b = bp / 3, p = bp - b * 3;
    int n0 = ntile * 64;
    int tr = threadIdx.x >> 6, tc = threadIdx.x & 63;

    const float* src = f + ((size_t)(p * B_ + b) * N_ + n0) * C_;
#pragma unroll
    for (int it = 0; it < 16; ++it) {
        int r = it * 4 + tr;
        tile[r][tc] = src[(size_t)r * C_ + tc];
    }
    __syncthreads();
    float* dst = out + (size_t)(b * 3 + p) * C_ * N_ + n0;
#pragma unroll
    for (int it = 0; it < 16; ++it) {
        int cidx = it * 4 + tr;
        dst[(size_t)cidx * N_ + tc] = tile[tc][cidx];
    }
}

extern "C" void kernel_launch(void* const* d_in, const int* in_sizes, int n_in,
                              void* d_out, int out_size, void* d_ws, size_t ws_size,
                              hipStream_t stream) {
    const float* img_feats = (const float*)d_in[0];
    const float* pts       = (const float*)d_in[1];
    const float* query     = (const float*)d_in[2];
    const float* ln1_g     = (const float*)d_in[3];
    const float* ln1_b     = (const float*)d_in[4];
    const float* ln2_g     = (const float*)d_in[5];
    const float* ln2_b     = (const float*)d_in[6];
    const float* in_w      = (const float*)d_in[7];
    const float* in_b      = (const float*)d_in[8];
    const float* out_w     = (const float*)d_in[9];
    const float* out_b     = (const float*)d_in[10];
    const float* ffn_w1    = (const float*)d_in[11];
    const float* ffn_b1    = (const float*)d_in[12];
    const float* ffn_w2    = (const float*)d_in[13];
    const float* ffn_b2    = (const float*)d_in[14];

    const size_t FEAT_SZ = (size_t)3 * B_ * N_ * C_;  // 6,291,456

    float* ws = (float*)d_ws;
    float* ftr      = ws;                                  // FTR_SZ floats
    int* counts     = (int*)(ftr + FTR_SZ);                // SEG_SZ
    int* offsets    = counts + SEG_SZ;                     // NSEG*OSTRIDE
    int* cursors    = offsets + (size_t)NSEG * OSTRIDE;    // SEG_SZ
    float4* ent     = (float4*)(cursors + SEG_SZ);         // SEG_SZ float4 (+8 pad)
    float* fA       = (float*)(ent + SEG_SZ + 8);
    float* fB       = fA + FEAT_SZ;
    unsigned short* pk_base = (unsigned short*)(fB + FEAT_SZ);
    // kv tables alias the (dead after gather_splat) counts/offsets region
    float* kvk = (float*)counts;
    float* kvv = kvk + KV_SZ;

    // ---- splat via binning + strip gather (no float atomics); query init fused
    zero_counts<<<(int)(SEG_SZ / 4 + 255) / 256, 256, 0, stream>>>((int4*)counts, (int)(SEG_SZ / 4));
    transpose_feats<<<NBV * 256, 256, 0, stream>>>(img_feats, ftr);
    bin_count<<<(NBV * N_) / 256, 256, 0, stream>>>(pts, counts);
    scan_bins<<<NSEG, 256, 0, stream>>>(counts, offsets, cursors);
    scatter_pts<<<(NBV * N_) / 256, 256, 0, stream>>>(pts, cursors, ent);
    gather_splat<<<dim3(2048, 3, B_), 512, 0, stream>>>(ftr, offsets, ent, query, fA);

    // pack weights
    for (int l = 0; l < NL_; ++l) {
        pack_layer<<<(PK_ELEMS + 255) / 256, 256, 0, stream>>>(
            in_w + (size_t)l * 3 * C_ * C_, out_w + (size_t)l * C_ * C_,
            ffn_w1 + (size_t)l * 4 * C_ * C_, ffn_w2 + (size_t)l * C_ * 4 * C_,
            pk_base + (size_t)l * LAYER_PK);
    }

    dim3 pgrid((B_ * N_) / 64, 3);
    for (int l = 0; l < NL_; ++l) {
        const float* fin = (l == 0) ? fA : fB;
        float* fout      = (l == 0) ? fB : fA;
        ctx_kv<<<144, 256, 0, stream>>>(fin, ln1_g + l * C_, ln1_b + l * C_,
                                        in_w + (size_t)l * 3 * C_ * C_, in_b + l * 3 * C_,
                                        kvk, kvv);
        plane_mfma<<<pgrid, 256, 0, stream>>>(
            fin, fout, pk_base + (size_t)l * LAYER_PK, kvk, kvv,
            ln1_g + l * C_, ln1_b + l * C_,
            ln2_g + l * C_, ln2_b + l * C_,
            in_b + l * 3 * C_, out_b + l * C_,
            ffn_b1 + l * 4 * C_, ffn_b2 + l * C_);
    }

    output_kernel<<<B_ * 3 * (N_ / 64), 256, 0, stream>>>(fA, (float*)d_out);
}

// Round 21
// 347.808 us; speedup vs baseline: 1.0812x; 1.0084x over previous
//
#include <hip/hip_runtime.h>
#include <math.h>

constexpr int R_ = 128, C_ = 64, NL_ = 2, B_ = 2, V_ = 4;
constexpr int N_ = R_ * R_;          // 16384
constexpr int T_ = 6;

typedef __attribute__((ext_vector_type(8))) short bf16x8;
typedef __attribute__((ext_vector_type(4))) float f32x4;
typedef __attribute__((ext_vector_type(4))) unsigned short u16x4;
typedef __attribute__((ext_vector_type(8))) unsigned short u16x8;
typedef __attribute__((ext_vector_type(2))) __fp16 h2;

#define MFMA_B16(a, b, c) __builtin_amdgcn_mfma_f32_16x16x32_bf16((a), (b), (c), 0, 0, 0)

// packed-weight element offsets (per layer, in elements)
constexpr int OFF_O = 12288, OFF_W1 = 16384, OFF_W2 = 32768;
constexpr int PK_ELEMS = 49152;
constexpr int LAYER_PK = 2 * PK_ELEMS;   // ushorts per layer (hi+lo)

// splat-path sizes
constexpr int NBV = B_ * V_;                       // 8
constexpr size_t FTR_SZ = (size_t)NBV * N_ * C_;   // 8,388,608 floats
constexpr int NSEG = 3 * NBV;                      // 24 segments
constexpr size_t SEG_SZ = (size_t)NSEG * N_;       // 393,216 ints
constexpr int OSTRIDE = N_ + 128;                  // offsets stride (sentinel pad)
constexpr size_t KV_SZ = (size_t)3 * B_ * T_ * 128 * 64;   // 294,912 floats

// ---------- helpers ----------
__device__ inline unsigned rne16(float x) {
    unsigned b = __float_as_uint(x);
    return (b + 0x7fffu + ((b >> 16) & 1u)) >> 16;
}

__device__ inline float wsum(float v) {
#pragma unroll
    for (int m = 1; m < 64; m <<= 1) v += __shfl_xor(v, m, 64);
    return v;
}

__device__ inline float lnorm(float v, float g, float b) {
    float m = wsum(v) * (1.f / 64.f);
    float d = v - m;
    float var = wsum(d * d) * (1.f / 64.f);
    return d * rsqrtf(var + 1e-5f) * g + b;
}

// stage a 64x64 row-major fp32 matrix into LDS buf[c*68 + u]
__device__ inline void stageW(const float* __restrict__ W, float* buf, int tid) {
#pragma unroll
    for (int it = 0; it < 4; ++it) {
        int idx4 = it * 256 + tid;
        int r = idx4 >> 4, u4 = idx4 & 15;
        float4 v = ((const float4*)W)[idx4];
        *(float4*)&buf[r * 68 + u4 * 4] = v;
    }
}

// read A-fragment (16x32 bf16) for wave's M-tile from swizzled LDS
__device__ inline bf16x8 readFrag(const unsigned short* base, int rowBase, int lane,
                                  int ks, int rowStrideB, int swzMask) {
    int rowloc = rowBase + (lane & 15);
    int off = rowloc * rowStrideB + ks * 64 + ((lane >> 4) & 3) * 16;
    off ^= ((rowloc & swzMask) << 4);
    return *(const bf16x8*)((const char*)base + off);
}

// store 4 bf16-hi values (K-permuted: p = cb*4+nt) as one 8B write
__device__ inline void storeA4(unsigned short* base, int rloc, int cb,
                               float v0, float v1, float v2, float v3) {
    u16x4 u;
    u[0] = (unsigned short)rne16(v0);
    u[1] = (unsigned short)rne16(v1);
    u[2] = (unsigned short)rne16(v2);
    u[3] = (unsigned short)rne16(v3);
    int bo = (rloc * 128 + cb * 8) ^ ((rloc & 7) << 4);
    *(u16x4*)((char*)base + bo) = u;
}

// load B-fragment pair (hi,lo) from a weight table (global or LDS)
__device__ inline void readB(const unsigned short* matHi, int E, int NTm, int ks, int nt,
                             int lane, bf16x8& bh, bf16x8& bl) {
    int off = (((ks * NTm + nt) << 6) + lane) << 3;
    bh = *(const bf16x8*)(matHi + off);
    bl = *(const bf16x8*)(matHi + E + off);
}

// ---------- pack all weights of one layer (K-permuted, split hi/lo) ----------
__global__ __launch_bounds__(256) void pack_layer(const float* __restrict__ iw,
                                                  const float* __restrict__ ow,
                                                  const float* __restrict__ w1,
                                                  const float* __restrict__ w2,
                                                  unsigned short* __restrict__ pk) {
    int idx = blockIdx.x * 256 + threadIdx.x;
    if (idx >= PK_ELEMS) return;
    const float* W;
    int O, K, base, mode, lidx;
    if (idx < 12288)      { int m = idx >> 12; lidx = idx & 4095; W = iw + m * 4096; O = 64;  K = 64;  base = m * 4096; mode = 0; }
    else if (idx < 16384) { lidx = idx - 12288; W = ow; O = 64;  K = 64;  base = OFF_O;  mode = 0; }
    else if (idx < 32768) { lidx = idx - 16384; W = w1; O = 256; K = 64;  base = OFF_W1; mode = 0; }
    else                  { lidx = idx - 32768; W = w2; O = 64;  K = 256; base = OFF_W2; mode = 1; }
    int j = lidx & 7, l = (lidx >> 3) & 63, rem = lidx >> 9;
    int NTm = O >> 4;
    int nt = rem & (NTm - 1), ks = rem / NTm;
    int kfrag = ks * 32 + ((l >> 4) & 3) * 8 + j;
    int k;
    if (mode == 0) { int p = kfrag & 63; k = (p & 3) * 16 + (p >> 2); }
    else { int cc = kfrag >> 7; int pl = kfrag & 127; k = (cc * 8 + (pl & 7)) * 16 + (pl >> 3); }
    int o = nt * 16 + (l & 15);
    float w = W[(size_t)o * K + k];
    unsigned hb = rne16(w);
    float hf = __uint_as_float(hb << 16);
    unsigned lb = rne16(w - hf);
    int E = O * K;
    pk[2 * base + lidx] = (unsigned short)hb;
    pk[2 * base + E + lidx] = (unsigned short)lb;
}

// ---------- zero bin counts ----------
__global__ __launch_bounds__(256) void zero_counts(int4* __restrict__ p, int n4) {
    int i = blockIdx.x * 256 + threadIdx.x;
    if (i < n4) p[i] = make_int4(0, 0, 0, 0);
}

// ---------- transpose features: [bv][c][n] -> [bv][n][c] ----------
__global__ __launch_bounds__(256) void transpose_feats(const float* __restrict__ src,
                                                       float* __restrict__ dst) {
    __shared__ float tile[64][65];
    int blk = blockIdx.x;             // NBV * 256
    int ntile = blk & 255;
    int bv = blk >> 8;
    int n0 = ntile * 64;
    int tr = threadIdx.x >> 6, tc = threadIdx.x & 63;
    const float* s = src + (size_t)bv * C_ * N_;
#pragma unroll
    for (int it = 0; it < 16; ++it) {
        int c = it * 4 + tr;
        tile[c][tc] = s[(size_t)c * N_ + n0 + tc];
    }
    __syncthreads();
    float* d = dst + ((size_t)bv * N_ + n0) * C_;
#pragma unroll
    for (int it = 0; it < 16; ++it) {
        int r = it * 4 + tr;
        d[(size_t)r * C_ + tc] = tile[tc][r];
    }
}

// ---------- bin count ----------
__global__ __launch_bounds__(256) void bin_count(const float* __restrict__ pts,
                                                 int* __restrict__ counts) {
    int idx = blockIdx.x * 256 + threadIdx.x;     // [0, NBV*N)
    if (idx >= NBV * N_) return;
    int bv = idx >> 14;
    const float* p = pts + (size_t)idx * 3;
    float px = p[0], py = p[1], pz = p[2];
    const float HI = (float)(127.0 - 1e-5);
    float gx = fminf(fmaxf((px + 1.0f) * 127.0f / 2.0f, 0.0f), HI);
    float gy = fminf(fmaxf((py + 1.0f) * 127.0f / 2.0f, 0.0f), HI);
    float gz = fminf(fmaxf((pz + 1.0f) * 127.0f / 2.0f, 0.0f), HI);
    int x0 = (int)gx, y0 = (int)gy, z0 = (int)gz;
    atomicAdd(&counts[(0 * NBV + bv) * N_ + x0 * R_ + y0], 1);
    atomicAdd(&counts[(1 * NBV + bv) * N_ + x0 * R_ + z0], 1);
    atomicAdd(&counts[(2 * NBV + bv) * N_ + y0 * R_ + z0], 1);
}

// ---------- per-segment exclusive scan (16384 bins each) + sentinel pad ----------
__global__ __launch_bounds__(256) void scan_bins(const int* __restrict__ counts,
                                                 int* __restrict__ offsets,
                                                 int* __restrict__ cursors) {
    __shared__ int part[256];
    int seg = blockIdx.x;             // 24
    int t = threadIdx.x;
    const int* c = counts + (size_t)seg * N_;
    int sum = 0;
    for (int i = 0; i < 64; ++i) sum += c[t * 64 + i];
    part[t] = sum;
    __syncthreads();
    if (t == 0) {
        int run = 0;
        for (int i = 0; i < 256; ++i) { int v = part[i]; part[i] = run; run += v; }
    }
    __syncthreads();
    int run = part[t];
    int* o = offsets + (size_t)seg * OSTRIDE;
    int* cu = cursors + (size_t)seg * N_;
    for (int i = 0; i < 64; ++i) {
        o[t * 64 + i] = run;
        cu[t * 64 + i] = run;
        run += c[t * 64 + i];
    }
    if (t < 128) o[N_ + t] = N_;      // sentinel: total per segment == N_
}

// ---------- scatter records (n, fp16 weight pairs) into bin-sorted lists ----------
__global__ __launch_bounds__(256) void scatter_pts(const float* __restrict__ pts,
                                                   int* __restrict__ cursors,
                                                   float4* __restrict__ ent) {
    int idx = blockIdx.x * 256 + threadIdx.x;
    if (idx >= NBV * N_) return;
    int bv = idx >> 14, n = idx & (N_ - 1);
    const float* p = pts + (size_t)idx * 3;
    float px = p[0], py = p[1], pz = p[2];
    const float HI = (float)(127.0 - 1e-5);
    float gx = fminf(fmaxf((px + 1.0f) * 127.0f / 2.0f, 0.0f), HI);
    float gy = fminf(fmaxf((py + 1.0f) * 127.0f / 2.0f, 0.0f), HI);
    float gz = fminf(fmaxf((pz + 1.0f) * 127.0f / 2.0f, 0.0f), HI);
    int x0 = (int)gx, y0 = (int)gy, z0 = (int)gz;
    float wx = gx - (float)x0, wy = gy - (float)y0, wz = gz - (float)z0;
    float ax = 1.f - wx, ay = 1.f - wy, az = 1.f - wz;
    float4 e;
    e.x = __uint_as_float((unsigned)n);
    e.w = 0.f;
    int s0 = 0 * NBV + bv, s1 = 1 * NBV + bv, s2 = 2 * NBV + bv;
    // plane0 (bin row x0, col y0): dr0 -> {w000, w010}; dr1 -> {w100, w110}
    {
        h2 a = __builtin_amdgcn_cvt_pkrtz(ax * ay * az, ax * wy * az);
        h2 bq = __builtin_amdgcn_cvt_pkrtz(wx * ay * az, wx * wy * az);
        e.y = *(float*)&a; e.z = *(float*)&bq;
        int p0 = atomicAdd(&cursors[(size_t)s0 * N_ + x0 * R_ + y0], 1);
        ent[(size_t)s0 * N_ + p0] = e;
    }
    // plane1 (bin row x0, col z0): dr0 -> {w000, w001}; dr1 -> {w100, w111}
    {
        h2 a = __builtin_amdgcn_cvt_pkrtz(ax * ay * az, ax * ay * wz);
        h2 bq = __builtin_amdgcn_cvt_pkrtz(wx * ay * az, wx * wy * wz);
        e.y = *(float*)&a; e.z = *(float*)&bq;
        int p1 = atomicAdd(&cursors[(size_t)s1 * N_ + x0 * R_ + z0], 1);
        ent[(size_t)s1 * N_ + p1] = e;
    }
    // plane2 (bin row y0, col z0): dr0 -> {w000, w001}; dr1 -> {w010, w111}
    {
        h2 a = __builtin_amdgcn_cvt_pkrtz(ax * ay * az, ax * ay * wz);
        h2 bq = __builtin_amdgcn_cvt_pkrtz(ax * wy * az, wx * wy * wz);
        e.y = *(float*)&a; e.z = *(float*)&bq;
        int p2 = atomicAdd(&cursors[(size_t)s2 * N_ + y0 * R_ + z0], 1);
        ent[(size_t)s2 * N_ + p2] = e;
    }
}

// ---------- gather splat: block = 8-cell strip; wave = (view, bin-row) ----------
// register accumulators (compile-time j), fp16 precomputed weights, fused query init
__global__ __launch_bounds__(512) void gather_splat(
    const float* __restrict__ ftr, const int* __restrict__ offsets,
    const float4* __restrict__ ent, const float* __restrict__ query,
    float* __restrict__ f0) {
    __shared__ float sfacc[8][8][64];
    __shared__ float swsum[8][8];
    int wid = threadIdx.x >> 6, lane = threadIdx.x & 63;
    int v = wid >> 1, dr = wid & 1;
    int strip = blockIdx.x;                   // [0, 2048)
    int pi = blockIdx.y, b = blockIdx.z;
    int a = strip >> 4;                       // cell row
    int c0 = (strip & 15) << 3;               // first cell col of strip

    int bv = b * V_ + v;
    int seg = pi * NBV + bv;
    const int* ob = offsets + (size_t)seg * OSTRIDE;
    const float4* eb = ent + (size_t)seg * N_;
    const float* fbase = ftr + (size_t)bv * N_ * C_ + lane;
    float facc[8], wsum_[8];
#pragma unroll
    for (int k = 0; k < 8; ++k) { facc[k] = 0.f; wsum_[k] = 0.f; }

    int ba = a - dr;
    if (ba >= 0) {
        int rowbase = ba * R_ + c0 - 1;
        int o[10];
#pragma unroll
        for (int jj = 0; jj < 10; ++jj)
            o[jj] = ob[max(rowbase + jj, 0)];
#pragma unroll
        for (int j = 0; j < 9; ++j) {
            if (j == 0 && c0 == 0) continue;    // bin col -1 doesn't exist
            int e = o[j + 1];
            for (int i = o[j]; i < e; ++i) {
                float4 r = eb[i];
                int n = (int)(__float_as_uint(r.x) & 16383u);
                float pr = dr ? r.z : r.y;
                h2 ph = *(h2*)&pr;
                float w0 = (float)ph[0], w1 = (float)ph[1];
                float f = fbase[(size_t)n * C_];
                if (j > 0) { facc[j - 1] += w0 * f; wsum_[j - 1] += w0; }
                if (j < 8) { facc[j] += w1 * f; wsum_[j] += w1; }
            }
        }
    }
#pragma unroll
    for (int k = 0; k < 8; ++k) sfacc[wid][k][lane] = facc[k];
    if (lane == 0) {
#pragma unroll
        for (int k = 0; k < 8; ++k) swsum[wid][k] = wsum_[k];
    }
    __syncthreads();

    // combine: wave wid handles cell k = wid (sum dr pair per view, then normalize)
    int k = wid;
    int cell = a * R_ + c0 + k;
    float tot = 0.f;
#pragma unroll
    for (int v2 = 0; v2 < 4; ++v2) {
        float fa = sfacc[v2 * 2][k][lane] + sfacc[v2 * 2 + 1][k][lane];
        float wsv = swsum[v2 * 2][k] + swsum[v2 * 2 + 1][k];
        tot += fa / fmaxf(wsv, 1e-8f);
    }
    float qv = query[((size_t)pi * N_ + cell) * C_ + lane];
    f0[(((size_t)(pi * B_ + b)) * N_ + cell) * C_ + lane] = qv + 0.25f * tot;
}

// ---------- ctx k/v table: 4608 rows = (pi, b, t, pos) ----------
__global__ __launch_bounds__(256) void ctx_kv(
    const float* __restrict__ fin,
    const float* __restrict__ ln1g, const float* __restrict__ ln1b,
    const float* __restrict__ inw, const float* __restrict__ inb,
    float* __restrict__ kvk, float* __restrict__ kvv) {
    __shared__ float s_wk[64 * 68];
    __shared__ float s_wv[64 * 68];
    __shared__ float s_act[32 * 68];
    int tid = threadIdx.x, wid = tid >> 6, lane = tid & 63;
    stageW(inw + 4096, s_wk, tid);     // Wk
    stageW(inw + 8192, s_wv, tid);     // Wv

    int rid0 = blockIdx.x * 32 + wid * 8;
    int seg = rid0 >> 7;               // (pi*2+b)*6 + t
    int pos0 = rid0 & 127;
    int t = seg % 6;
    int pib = seg / 6;
    int pi = pib >> 1, b = pib & 1;
    int khalf = (t < 3) ? t : t - 3;
    float sk = (float)(khalf - 1);
    bool tl = t < 3;
    int io;
    if (pi == 0) io = tl ? 1 : 2;
    else if (pi == 1) io = tl ? 0 : 2;
    else io = tl ? 0 : 1;
    const float* Fio = fin + (size_t)(io * B_ + b) * N_ * 64;
    float g1 = ln1g[lane], b1 = ln1b[lane];

#pragma unroll
    for (int rr = 0; rr < 8; ++rr) {
        int pos = pos0 + rr;
        float lp = -1.0f + (2.0f * (float)pos) / 127.0f;
        float caf, cbf;
        if (pi == 0) { caf = lp; cbf = sk; }
        else if (pi == 1) { if (tl) { caf = lp; cbf = sk; } else { caf = sk; cbf = lp; } }
        else { caf = sk; cbf = lp; }
        float ua = fminf(fmaxf((caf * 0.5f + 0.5f) * 127.0f, 0.0f), 127.0f);
        float ub = fminf(fmaxf((cbf * 0.5f + 0.5f) * 127.0f, 0.0f), 127.0f);
        float gxp = fminf(fmaxf(((ua + 1.0f) * 0.5f) * 127.0f, 0.0f), 127.0f);
        float gyp = fminf(fmaxf(((ub + 1.0f) * 0.5f) * 127.0f, 0.0f), 127.0f);
        int xx0 = (int)gxp, yy0 = (int)gyp;
        int xx1 = xx0 + 1 < 128 ? xx0 + 1 : 127;
        int yy1 = yy0 + 1 < 128 ? yy0 + 1 : 127;
        float wx = gxp - (float)xx0, wy = gyp - (float)yy0;
        float v00 = Fio[(size_t)(yy0 * R_ + xx0) * 64 + lane];
        float v01 = Fio[(size_t)(yy0 * R_ + xx1) * 64 + lane];
        float v10 = Fio[(size_t)(yy1 * R_ + xx0) * 64 + lane];
        float v11 = Fio[(size_t)(yy1 * R_ + xx1) * 64 + lane];
        float cv = (1.0f - wy) * ((1.0f - wx) * v00 + wx * v01) +
                   wy * ((1.0f - wx) * v10 + wx * v11);
        s_act[(wid * 8 + rr) * 68 + lane] = lnorm(cv, g1, b1);
    }
    __syncthreads();

    float kk[8], vv[8];
    float bk = inb[64 + lane], bv = inb[128 + lane];
#pragma unroll
    for (int rr = 0; rr < 8; ++rr) { kk[rr] = bk; vv[rr] = bv; }
    const float* wrk = s_wk + lane * 68;
    const float* wrv = s_wv + lane * 68;
#pragma unroll 4
    for (int g = 0; g < 16; ++g) {
        float4 wk4 = *(const float4*)(wrk + g * 4);
        float4 wv4 = *(const float4*)(wrv + g * 4);
#pragma unroll
        for (int rr = 0; rr < 8; ++rr) {
            float4 xv = *(const float4*)(s_act + (wid * 8 + rr) * 68 + g * 4);
            kk[rr] = fmaf(xv.x, wk4.x, fmaf(xv.y, wk4.y, fmaf(xv.z, wk4.z, fmaf(xv.w, wk4.w, kk[rr]))));
            vv[rr] = fmaf(xv.x, wv4.x, fmaf(xv.y, wv4.y, fmaf(xv.z, wv4.z, fmaf(xv.w, wv4.w, vv[rr]))));
        }
    }
#pragma unroll
    for (int rr = 0; rr < 8; ++rr) {
        size_t o = ((size_t)seg * 128 + pos0 + rr) * 64 + lane;
        kvk[o] = kk[rr];
        kvv[o] = vv[rr];
    }
}

// ---------- fused per-plane transformer layer (MFMA, precomputed k/v) ----------
// dout != nullptr: final layer writes transposed (b,p,c,n) directly to d_out
__global__ __launch_bounds__(256, 2) void plane_mfma(
    const float* __restrict__ fin, float* __restrict__ fout,
    float* __restrict__ dout,
    const unsigned short* __restrict__ pk,
    const float* __restrict__ kvk, const float* __restrict__ kvv,
    const float* __restrict__ ln1g, const float* __restrict__ ln1b,
    const float* __restrict__ ln2g, const float* __restrict__ ln2b,
    const float* __restrict__ inb, const float* __restrict__ outb,
    const float* __restrict__ fb1, const float* __restrict__ fb2) {
    __shared__ __attribute__((aligned(16))) unsigned short Wb[16384];  // 32 KB weight stage
    __shared__ __attribute__((aligned(16))) unsigned short Ahi[4096];  // 8 KB A-frags
    __shared__ __attribute__((aligned(16))) float Hf[4096];            // 16 KB H-frags / out stage
    unsigned short* Hhi = (unsigned short*)Hf;

    const int tid = threadIdx.x;
    const int wid = tid >> 6, lane = tid & 63;
    const int cg = lane >> 4, cb = lane & 15;
    const int pi = blockIdx.y;
    const int R0 = wid * 16;
    const int rowbase = blockIdx.x * 64;
    const int b = rowbase >> 14;
    const int nn0 = rowbase & (N_ - 1);
    const int i0 = nn0 >> 7, j0 = nn0 & 127;

    // ---- stage Q (16 KB) into Wb[0:8192] AND O (16 KB) into Wb[8192:16384]
#pragma unroll
    for (int i = 0; i < 4; ++i)
        *(u16x8*)(Wb + (i * 256 + tid) * 8) = *(const u16x8*)(pk + (i * 256 + tid) * 8);
#pragma unroll
    for (int i = 0; i < 4; ++i)
        *(u16x8*)(Wb + 8192 + (i * 256 + tid) * 8) = *(const u16x8*)(pk + 24576 + (i * 256 + tid) * 8);

    float g1[4], b1v[4];
#pragma unroll
    for (int nt = 0; nt < 4; ++nt) { g1[nt] = ln1g[nt * 16 + cb]; b1v[nt] = ln1b[nt * 16 + cb]; }

    // ---- Phase A: load x (kept in regs), LN1 -> A-frags (wave-private LDS rows)
    float x[4][4];
    const float* finp = fin + ((size_t)(pi * B_ + b) * N_ + nn0) * 64;
#pragma unroll
    for (int reg = 0; reg < 4; ++reg) {
        int rloc = R0 + cg * 4 + reg;
#pragma unroll
        for (int nt = 0; nt < 4; ++nt) x[reg][nt] = finp[(size_t)rloc * 64 + nt * 16 + cb];
        float s = x[reg][0] + x[reg][1] + x[reg][2] + x[reg][3];
#pragma unroll
        for (int m = 1; m < 16; m <<= 1) s += __shfl_xor(s, m, 64);
        float mean = s * (1.0f / 64.0f);
        float d0 = x[reg][0] - mean, d1 = x[reg][1] - mean, d2 = x[reg][2] - mean, d3 = x[reg][3] - mean;
        float sq = d0 * d0 + d1 * d1 + d2 * d2 + d3 * d3;
#pragma unroll
        for (int m = 1; m < 16; m <<= 1) sq += __shfl_xor(sq, m, 64);
        float rr = rsqrtf(sq * (1.0f / 64.0f) + 1e-5f);
        storeA4(Ahi, rloc, cb,
                d0 * rr * g1[0] + b1v[0], d1 * rr * g1[1] + b1v[1],
                d2 * rr * g1[2] + b1v[2], d3 * rr * g1[3] + b1v[3]);
    }
    __syncthreads();     // Q+O staged; LN1 A-frags ready

    // ---- Phase B: q = xn @ Wq^T + bq  (Wb[0:8192] = Q)
    f32x4 qa[4];
#pragma unroll
    for (int nt = 0; nt < 4; ++nt) { float bq = inb[nt * 16 + cb]; qa[nt] = {bq, bq, bq, bq}; }
#pragma unroll
    for (int ks = 0; ks < 2; ++ks) {
        bf16x8 ah = readFrag(Ahi, R0, lane, ks, 128, 7);
#pragma unroll
        for (int nt = 0; nt < 4; ++nt) {
            bf16x8 bh, bl;
            readB(Wb, 4096, 4, ks, nt, lane, bh, bl);
            qa[nt] = MFMA_B16(ah, bh, qa[nt]);
            qa[nt] = MFMA_B16(ah, bl, qa[nt]);
        }
    }

    // ---- Phase C: attention with precomputed k/v (no barriers, no LDS)
    const float* kvkb = kvk + (size_t)((pi * 2 + b) * 6) * 128 * 64;
    const float* kvvb = kvv + (size_t)((pi * 2 + b) * 6) * 128 * 64;
    float den_[4][4];
    f32x4 oa[4];
#pragma unroll
    for (int nt = 0; nt < 4; ++nt) {
        oa[nt] = {0.f, 0.f, 0.f, 0.f};
#pragma unroll
        for (int reg = 0; reg < 4; ++reg) den_[nt][reg] = 0.f;
    }

    // t = 0..2: k/v depend on j (per-row)
#pragma unroll
    for (int t = 0; t < 3; ++t) {
        float kvr[4][4], vvr[4][4];
#pragma unroll
        for (int reg = 0; reg < 4; ++reg) {
            int pos = j0 + R0 + cg * 4 + reg;
            const float* kr = kvkb + ((size_t)t * 128 + pos) * 64 + cb;
            const float* vr = kvvb + ((size_t)t * 128 + pos) * 64 + cb;
#pragma unroll
            for (int nt = 0; nt < 4; ++nt) {
                kvr[reg][nt] = kr[nt * 16];
                vvr[reg][nt] = vr[nt * 16];
            }
        }
#pragma unroll
        for (int nt = 0; nt < 4; ++nt) {
            float d0 = qa[nt][0] * kvr[0][nt];
            float d1 = qa[nt][1] * kvr[1][nt];
            float d2 = qa[nt][2] * kvr[2][nt];
            float d3 = qa[nt][3] * kvr[3][nt];
#pragma unroll
            for (int m = 1; m < 16; m <<= 1) {
                d0 += __shfl_xor(d0, m, 64);
                d1 += __shfl_xor(d1, m, 64);
                d2 += __shfl_xor(d2, m, 64);
                d3 += __shfl_xor(d3, m, 64);
            }
            float e0 = __expf(d0 * 0.25f), e1 = __expf(d1 * 0.25f);
            float e2 = __expf(d2 * 0.25f), e3 = __expf(d3 * 0.25f);
            den_[nt][0] += e0; den_[nt][1] += e1; den_[nt][2] += e2; den_[nt][3] += e3;
            oa[nt][0] += e0 * vvr[0][nt];
            oa[nt][1] += e1 * vvr[1][nt];
            oa[nt][2] += e2 * vvr[2][nt];
            oa[nt][3] += e3 * vvr[3][nt];
        }
    }
    // t = 3..5: k/v depend on i (block-uniform row i0)
#pragma unroll
    for (int t = 3; t < 6; ++t) {
        float ku[4], vu[4];
        const float* kr = kvkb + ((size_t)t * 128 + i0) * 64 + cb;
        const float* vr = kvvb + ((size_t)t * 128 + i0) * 64 + cb;
#pragma unroll
        for (int nt = 0; nt < 4; ++nt) { ku[nt] = kr[nt * 16]; vu[nt] = vr[nt * 16]; }
#pragma unroll
        for (int nt = 0; nt < 4; ++nt) {
            float d0 = qa[nt][0] * ku[nt];
            float d1 = qa[nt][1] * ku[nt];
            float d2 = qa[nt][2] * ku[nt];
            float d3 = qa[nt][3] * ku[nt];
#pragma unroll
            for (int m = 1; m < 16; m <<= 1) {
                d0 += __shfl_xor(d0, m, 64);
                d1 += __shfl_xor(d1, m, 64);
                d2 += __shfl_xor(d2, m, 64);
                d3 += __shfl_xor(d3, m, 64);
            }
            float e0 = __expf(d0 * 0.25f), e1 = __expf(d1 * 0.25f);
            float e2 = __expf(d2 * 0.25f), e3 = __expf(d3 * 0.25f);
            den_[nt][0] += e0; den_[nt][1] += e1; den_[nt][2] += e2; den_[nt][3] += e3;
            oa[nt][0] += e0 * vu[nt];
            oa[nt][1] += e1 * vu[nt];
            oa[nt][2] += e2 * vu[nt];
            oa[nt][3] += e3 * vu[nt];
        }
    }

    // ---- write o/den -> A-frags (wave-private rows; DS in-order per wave, no barrier)
#pragma unroll
    for (int reg = 0; reg < 4; ++reg) {
        int rloc = R0 + cg * 4 + reg;
        storeA4(Ahi, rloc, cb,
                oa[0][reg] / den_[0][reg], oa[1][reg] / den_[1][reg],
                oa[2][reg] / den_[2][reg], oa[3][reg] / den_[3][reg]);
    }

    // ---- Phase D: out-proj (Wb[8192:] = O, pre-staged); residual; LN2 -> A-frags
    f32x4 ao[4];
#pragma unroll
    for (int nt = 0; nt < 4; ++nt) { float bo_ = outb[nt * 16 + cb]; ao[nt] = {bo_, bo_, bo_, bo_}; }
#pragma unroll
    for (int ks = 0; ks < 2; ++ks) {
        bf16x8 ah = readFrag(Ahi, R0, lane, ks, 128, 7);
#pragma unroll
        for (int nt = 0; nt < 4; ++nt) {
            bf16x8 bh, bl;
            readB(Wb + 8192, 4096, 4, ks, nt, lane, bh, bl);
            ao[nt] = MFMA_B16(ah, bh, ao[nt]);
            ao[nt] = MFMA_B16(ah, bl, ao[nt]);
        }
    }
    float g2[4], b2v[4];
#pragma unroll
    for (int nt = 0; nt < 4; ++nt) { g2[nt] = ln2g[nt * 16 + cb]; b2v[nt] = ln2b[nt * 16 + cb]; }
    float x2[4][4];
#pragma unroll
    for (int reg = 0; reg < 4; ++reg) {
        int rloc = R0 + cg * 4 + reg;
#pragma unroll
        for (int nt = 0; nt < 4; ++nt) x2[reg][nt] = x[reg][nt] + ao[nt][reg];
        float s = x2[reg][0] + x2[reg][1] + x2[reg][2] + x2[reg][3];
#pragma unroll
        for (int m = 1; m < 16; m <<= 1) s += __shfl_xor(s, m, 64);
        float mean = s * (1.0f / 64.0f);
        float d0 = x2[reg][0] - mean, d1 = x2[reg][1] - mean, d2 = x2[reg][2] - mean, d3 = x2[reg][3] - mean;
        float sq = d0 * d0 + d1 * d1 + d2 * d2 + d3 * d3;
#pragma unroll
        for (int m = 1; m < 16; m <<= 1) sq += __shfl_xor(sq, m, 64);
        float rr = rsqrtf(sq * (1.0f / 64.0f) + 1e-5f);
        storeA4(Ahi, rloc, cb,
                d0 * rr * g2[0] + b2v[0], d1 * rr * g2[1] + b2v[1],
                d2 * rr * g2[2] + b2v[2], d3 * rr * g2[3] + b2v[3]);
    }
    __syncthreads();     // Q/O reads done everywhere; Wb free for FFN staging

    // ---- Phase E: FFN 64->256 (gelu) ->64, 2 chunks of 128 hidden, staged weights
    const unsigned short* pW1 = pk + 2 * OFF_W1;
    const unsigned short* pW2 = pk + 2 * OFF_W2;
    f32x4 ya[4];
#pragma unroll
    for (int nt = 0; nt < 4; ++nt) { float by = fb2[nt * 16 + cb]; ya[nt] = {by, by, by, by}; }

#pragma unroll
    for (int cc = 0; cc < 2; ++cc) {
        // stage W1 chunk cc (32 KB): global tile gt=ks*16+cc*8+n8 -> lds tile lt=ks*8+n8
#pragma unroll
        for (int it = 0; it < 8; ++it) {
            int i = it * 256 + tid;
            int half = i >> 10, j = i & 1023;
            int lt = j >> 6, lr = j & 63;
            int ksl = lt >> 3, n8 = lt & 7;
            int gt = ksl * 16 + cc * 8 + n8;
            *(u16x8*)(Wb + half * 8192 + (lt * 64 + lr) * 8) =
                *(const u16x8*)(pW1 + half * 16384 + (gt * 64 + lr) * 8);
        }
        __syncthreads();

        f32x4 ha[8];
#pragma unroll
        for (int n8 = 0; n8 < 8; ++n8) {
            float hb = fb1[(cc * 8 + n8) * 16 + cb];
            ha[n8] = {hb, hb, hb, hb};
        }
#pragma unroll
        for (int ks = 0; ks < 2; ++ks) {
            bf16x8 ah = readFrag(Ahi, R0, lane, ks, 128, 7);
#pragma unroll
            for (int n8 = 0; n8 < 8; ++n8) {
                bf16x8 bh, bl;
                readB(Wb, 8192, 8, ks, n8, lane, bh, bl);
                ha[n8] = MFMA_B16(ah, bh, ha[n8]);
                ha[n8] = MFMA_B16(ah, bl, ha[n8]);
            }
        }
        // gelu -> H frags (wave-private rows)
#pragma unroll
        for (int reg = 0; reg < 4; ++reg) {
            int rloc = R0 + cg * 4 + reg;
            u16x8 u;
#pragma unroll
            for (int n8 = 0; n8 < 8; ++n8) {
                float h = ha[n8][reg];
                h = 0.5f * h * (1.0f + erff(h * 0.70710678118654752f));
                u[n8] = (unsigned short)rne16(h);
            }
            int bo = (rloc * 256 + cb * 16) ^ ((rloc & 15) << 4);
            *(u16x8*)((char*)Hhi + bo) = u;
        }
        __syncthreads();     // W1 reads done

        // stage W2 chunk cc (32 KB): contiguous tiles [cc*16, cc*16+16)
#pragma unroll
        for (int it = 0; it < 8; ++it) {
            int i = it * 256 + tid;
            int half = i >> 10, j = i & 1023;
            *(u16x8*)(Wb + half * 8192 + j * 8) =
                *(const u16x8*)(pW2 + half * 16384 + cc * 8192 + j * 8);
        }
        __syncthreads();

#pragma unroll
        for (int ks2 = 0; ks2 < 4; ++ks2) {
            bf16x8 ah = readFrag(Hhi, R0, lane, ks2, 256, 15);
            int ksg = cc * 4 + ks2;
            (void)ksg;
#pragma unroll
            for (int nt = 0; nt < 4; ++nt) {
                bf16x8 bh, bl;
                readB(Wb, 8192, 4, ks2, nt, lane, bh, bl);
                ya[nt] = MFMA_B16(ah, bh, ya[nt]);
                ya[nt] = MFMA_B16(ah, bl, ya[nt]);
            }
        }
        __syncthreads();     // W2 reads done before next chunk restage
    }

    if (dout == nullptr) {
        // ---- final: x2 + ffn -> Hf (linear rows), coalesced float4 store to fout
#pragma unroll
        for (int reg = 0; reg < 4; ++reg) {
            int rloc = R0 + cg * 4 + reg;
#pragma unroll
            for (int nt = 0; nt < 4; ++nt)
                Hf[rloc * 64 + nt * 16 + cb] = x2[reg][nt] + ya[nt][reg];
        }
        __syncthreads();
        float4* dst4 = (float4*)(fout + ((size_t)(pi * B_ + b) * N_ + nn0) * 64);
        const float4* src4 = (const float4*)Hf;
#pragma unroll
        for (int it = 0; it < 4; ++it) {
            int i = it * 256 + tid;
            dst4[i] = src4[i];
        }
    } else {
        // ---- final (fused output transpose): swizzled Hf store, write (b,p,c,n)
#pragma unroll
        for (int reg = 0; reg < 4; ++reg) {
            int rloc = R0 + cg * 4 + reg;
#pragma unroll
            for (int nt = 0; nt < 4; ++nt) {
                int ch = nt * 16 + cb;
                Hf[rloc * 64 + ((ch + rloc) & 63)] = x2[reg][nt] + ya[nt][reg];
            }
        }
        __syncthreads();
        float* dst = dout + (size_t)(b * 3 + pi) * C_ * N_ + nn0;
#pragma unroll
        for (int it = 0; it < 16; ++it) {
            int ch = it * 4 + wid;              // wave-uniform channel
            float val = Hf[lane * 64 + ((ch + lane) & 63)];
            dst[(size_t)ch * N_ + lane] = val;
        }
    }
}

extern "C" void kernel_launch(void* const* d_in, const int* in_sizes, int n_in,
                              void* d_out, int out_size, void* d_ws, size_t ws_size,
                              hipStream_t stream) {
    const float* img_feats = (const float*)d_in[0];
    const float* pts       = (const float*)d_in[1];
    const float* query     = (const float*)d_in[2];
    const float* ln1_g     = (const float*)d_in[3];
    const float* ln1_b     = (const float*)d_in[4];
    const float* ln2_g     = (const float*)d_in[5];
    const float* ln2_b     = (const float*)d_in[6];
    const float* in_w      = (const float*)d_in[7];
    const float* in_b      = (const float*)d_in[8];
    const float* out_w     = (const float*)d_in[9];
    const float* out_b     = (const float*)d_in[10];
    const float* ffn_w1    = (const float*)d_in[11];
    const float* ffn_b1    = (const float*)d_in[12];
    const float* ffn_w2    = (const float*)d_in[13];
    const float* ffn_b2    = (const float*)d_in[14];

    const size_t FEAT_SZ = (size_t)3 * B_ * N_ * C_;  // 6,291,456

    float* ws = (float*)d_ws;
    float* ftr      = ws;                                  // FTR_SZ floats
    int* counts     = (int*)(ftr + FTR_SZ);                // SEG_SZ
    int* offsets    = counts + SEG_SZ;                     // NSEG*OSTRIDE
    int* cursors    = offsets + (size_t)NSEG * OSTRIDE;    // SEG_SZ
    float4* ent     = (float4*)(cursors + SEG_SZ);         // SEG_SZ float4 (+8 pad)
    float* fA       = (float*)(ent + SEG_SZ + 8);
    float* fB       = fA + FEAT_SZ;
    unsigned short* pk_base = (unsigned short*)(fB + FEAT_SZ);
    // kv tables alias the (dead after gather_splat) counts/offsets region
    float* kvk = (float*)counts;
    float* kvv = kvk + KV_SZ;

    // ---- splat via binning + strip gather (no float atomics); query init fused
    zero_counts<<<(int)(SEG_SZ / 4 + 255) / 256, 256, 0, stream>>>((int4*)counts, (int)(SEG_SZ / 4));
    transpose_feats<<<NBV * 256, 256, 0, stream>>>(img_feats, ftr);
    bin_count<<<(NBV * N_) / 256, 256, 0, stream>>>(pts, counts);
    scan_bins<<<NSEG, 256, 0, stream>>>(counts, offsets, cursors);
    scatter_pts<<<(NBV * N_) / 256, 256, 0, stream>>>(pts, cursors, ent);
    gather_splat<<<dim3(2048, 3, B_), 512, 0, stream>>>(ftr, offsets, ent, query, fA);

    // pack weights
    for (int l = 0; l < NL_; ++l) {
        pack_layer<<<(PK_ELEMS + 255) / 256, 256, 0, stream>>>(
            in_w + (size_t)l * 3 * C_ * C_, out_w + (size_t)l * C_ * C_,
            ffn_w1 + (size_t)l * 4 * C_ * C_, ffn_w2 + (size_t)l * C_ * 4 * C_,
            pk_base + (size_t)l * LAYER_PK);
    }

    dim3 pgrid((B_ * N_) / 64, 3);
    for (int l = 0; l < NL_; ++l) {
        const float* fin = (l == 0) ? fA : fB;
        float* fout      = (l == 0) ? fB : fA;
        float* doutp     = (l == NL_ - 1) ? (float*)d_out : nullptr;
        ctx_kv<<<144, 256, 0, stream>>>(fin, ln1_g + l * C_, ln1_b + l * C_,
                                        in_w + (size_t)l * 3 * C_ * C_, in_b + l * 3 * C_,
                                        kvk, kvv);
        plane_mfma<<<pgrid, 256, 0, stream>>>(
            fin, fout, doutp, pk_base + (size_t)l * LAYER_PK, kvk, kvv,
            ln1_g + l * C_, ln1_b + l * C_,
            ln2_g + l * C_, ln2_b + l * C_,
            in_b + l * 3 * C_, out_b + l * C_,
            ffn_b1 + l * 4 * C_, ffn_b2 + l * C_);
    }
}